// Round 1
// baseline (2164.514 us; speedup 1.0000x reference)
//
#include <hip/hip_runtime.h>

// Round 0: correctness-first. fp32 pre-gate path (routing must match ref
// bit-robustly: a single top-2 flip costs ~0.5 absmax vs threshold 0.123),
// bf16 MFMA for the expert MLPs (smooth path, 72% of FLOPs).

typedef unsigned short u16;
typedef short bf16x8 __attribute__((ext_vector_type(8)));
typedef float f32x4 __attribute__((ext_vector_type(4)));

#define T_TOKENS 4096
#define SEQ      2048
#define CAPACITY 1280

__device__ __forceinline__ u16 f2bf(float f) {
  unsigned int u = __float_as_uint(f);
  return (u16)((u + 0x7FFFu + ((u >> 16) & 1u)) >> 16);
}
__device__ __forceinline__ float bf2f(u16 h) {
  return __uint_as_float(((unsigned int)h) << 16);
}
__device__ __forceinline__ float gelu_f(float x) {
  float x3 = x * x * x;
  float t = tanhf(0.7978845608028654f * (x + 0.044715f * x3));
  return 0.5f * x * (1.0f + t);
}

// ---------------- LayerNorm (fp32 in, fp32 and/or bf16 out) ----------------
__global__ __launch_bounds__(256) void ln_kernel(
    const float* __restrict__ x, const float* __restrict__ g,
    const float* __restrict__ bt, float* __restrict__ of32,
    u16* __restrict__ obf) {
  const int t = blockIdx.x, tid = threadIdx.x;
  float4 v = ((const float4*)(x + (size_t)t * 1024))[tid];
  float s = v.x + v.y + v.z + v.w;
  float sq = v.x * v.x + v.y * v.y + v.z * v.z + v.w * v.w;
#pragma unroll
  for (int d = 1; d < 64; d <<= 1) {
    s += __shfl_xor(s, d);
    sq += __shfl_xor(sq, d);
  }
  __shared__ float red[8];
  if ((tid & 63) == 0) { red[tid >> 6] = s; red[4 + (tid >> 6)] = sq; }
  __syncthreads();
  s = red[0] + red[1] + red[2] + red[3];
  sq = red[4] + red[5] + red[6] + red[7];
  const float mu = s * (1.0f / 1024.0f);
  const float var = sq * (1.0f / 1024.0f) - mu * mu;
  const float rs = rsqrtf(var + 1e-6f);
  float4 gv = ((const float4*)g)[tid];
  float4 bv = ((const float4*)bt)[tid];
  float4 o;
  o.x = (v.x - mu) * rs * gv.x + bv.x;
  o.y = (v.y - mu) * rs * gv.y + bv.y;
  o.z = (v.z - mu) * rs * gv.z + bv.z;
  o.w = (v.w - mu) * rs * gv.w + bv.w;
  if (of32) ((float4*)(of32 + (size_t)t * 1024))[tid] = o;
  if (obf) {
    ushort4 ob;
    ob.x = f2bf(o.x); ob.y = f2bf(o.y); ob.z = f2bf(o.z); ob.w = f2bf(o.w);
    ((ushort4*)(obf + (size_t)t * 1024))[tid] = ob;
  }
}

// ---------------- fp32 SGEMM: C[M,N] = A[M,K] @ B[K,N] + bias (+res) -------
// EPI 0: C = A@B + bias ; EPI 1: C = A@B + bias + res
template <int EPI>
__global__ __launch_bounds__(256, 2) void sgemm(
    const float* __restrict__ A, const float* __restrict__ B,
    const float* __restrict__ bias, const float* __restrict__ res,
    float* __restrict__ C, int M, int N, int K) {
  __shared__ float As[16][132];  // A^T tile: [k][m]
  __shared__ float Bs[16][132];  // [k][n]
  const int tid = threadIdx.x;
  const int m0 = blockIdx.y * 128, n0 = blockIdx.x * 128;
  const int tr = tid >> 4, tc = tid & 15;
  float acc[8][8] = {};

  for (int k0 = 0; k0 < K; k0 += 16) {
    // prefetch to regs
    const int r = tid >> 1, hf = tid & 1;
    const float* ga = A + (size_t)(m0 + r) * K + k0 + hf * 8;
    float4 a0 = ((const float4*)ga)[0];
    float4 a1 = ((const float4*)ga)[1];
    const int kk = tid >> 4, nq = tid & 15;
    const float* gb = B + (size_t)(k0 + kk) * N + n0 + nq * 8;
    float4 b0 = ((const float4*)gb)[0];
    float4 b1 = ((const float4*)gb)[1];
    __syncthreads();
    const int kb = hf * 8;
    As[kb + 0][r] = a0.x; As[kb + 1][r] = a0.y; As[kb + 2][r] = a0.z; As[kb + 3][r] = a0.w;
    As[kb + 4][r] = a1.x; As[kb + 5][r] = a1.y; As[kb + 6][r] = a1.z; As[kb + 7][r] = a1.w;
    *(float4*)&Bs[kk][nq * 8] = b0;
    *(float4*)&Bs[kk][nq * 8 + 4] = b1;
    __syncthreads();
#pragma unroll
    for (int k = 0; k < 16; ++k) {
      const float4 qa0 = *(const float4*)&As[k][tr * 8];
      const float4 qa1 = *(const float4*)&As[k][tr * 8 + 4];
      const float4 qb0 = *(const float4*)&Bs[k][tc * 8];
      const float4 qb1 = *(const float4*)&Bs[k][tc * 8 + 4];
      const float av[8] = {qa0.x, qa0.y, qa0.z, qa0.w, qa1.x, qa1.y, qa1.z, qa1.w};
      const float bv[8] = {qb0.x, qb0.y, qb0.z, qb0.w, qb1.x, qb1.y, qb1.z, qb1.w};
#pragma unroll
      for (int i = 0; i < 8; ++i)
#pragma unroll
        for (int j = 0; j < 8; ++j) acc[i][j] = fmaf(av[i], bv[j], acc[i][j]);
    }
  }
#pragma unroll
  for (int i = 0; i < 8; ++i) {
    const size_t row = (size_t)(m0 + tr * 8 + i);
    const int colb = n0 + tc * 8;
    float outv[8];
#pragma unroll
    for (int j = 0; j < 8; ++j) outv[j] = acc[i][j] + bias[colb + j];
    if (EPI == 1) {
      const float* rp = res + row * N + colb;
#pragma unroll
      for (int j = 0; j < 8; ++j) outv[j] += rp[j];
    }
    float* cp = C + row * N + colb;
    *(float4*)cp = make_float4(outv[0], outv[1], outv[2], outv[3]);
    *(float4*)(cp + 4) = make_float4(outv[4], outv[5], outv[6], outv[7]);
  }
}

// ---------------- RoPE (in-place on fp32 qkv, q pre-scaled by 1/8) ---------
__global__ __launch_bounds__(256) void rope_kernel(
    float* __restrict__ qkv, const float* __restrict__ cosb,
    const float* __restrict__ sinb) {
  const int t = blockIdx.x;
  const int s = t & (SEQ - 1);
  float* row = qkv + (size_t)t * 3072;
  const int tid = threadIdx.x;
#pragma unroll
  for (int it = 0; it < 4; ++it) {
    const int p = tid + it * 256;           // 1024 pairs
    const int sec = p >> 9;                 // 0=q, 1=k
    const int rem = p & 511;
    const int h = rem >> 5, d = rem & 31;
    const int col = sec * 1024 + h * 64 + d;
    const float c1 = cosb[s * 64 + d], s1 = sinb[s * 64 + d];
    const float c2 = cosb[s * 64 + d + 32], s2 = sinb[s * 64 + d + 32];
    const float a = row[col], b = row[col + 32];
    float na = a * c1 - b * s1;
    float nb = b * c2 + a * s2;
    if (sec == 0) { na *= 0.125f; nb *= 0.125f; }
    row[col] = na;
    row[col + 32] = nb;
  }
}

// ---------------- fp32 flash attention ------------------------------------
// grid (S/64, B*H), 256 threads. 64 q-rows per block, 64-key chunks.
__global__ __launch_bounds__(256, 2) void attn_f32(
    const float* __restrict__ qkv, float* __restrict__ o) {
  const int bh = blockIdx.y;
  const int b = bh >> 4, h = bh & 15;
  const int tid = threadIdx.x;
  const int qr = tid >> 4;  // 0..15
  const int qc = tid & 15;  // 0..15
  const float* base = qkv + (size_t)b * SEQ * 3072 + h * 64;
  const int q0 = blockIdx.x * 64;

  __shared__ float Qt[64][64];  // [d][q]
  __shared__ float Kt[64][64];  // [d][k]
  __shared__ float Vs[64][64];  // [k][d], d-group xor-swizzled by (k&15)
  __shared__ float Pt[64][64];  // [k][q], q-group xor-swizzled by (k&15)

  {  // stage Q^T once
    const int q = tid >> 2, dg = (tid & 3) * 16;
    const float* src = base + (size_t)(q0 + q) * 3072 + dg;
    float4 v0 = ((const float4*)src)[0];
    float4 v1 = ((const float4*)src)[1];
    float4 v2 = ((const float4*)src)[2];
    float4 v3 = ((const float4*)src)[3];
    Qt[dg + 0][q] = v0.x; Qt[dg + 1][q] = v0.y; Qt[dg + 2][q] = v0.z; Qt[dg + 3][q] = v0.w;
    Qt[dg + 4][q] = v1.x; Qt[dg + 5][q] = v1.y; Qt[dg + 6][q] = v1.z; Qt[dg + 7][q] = v1.w;
    Qt[dg + 8][q] = v2.x; Qt[dg + 9][q] = v2.y; Qt[dg + 10][q] = v2.z; Qt[dg + 11][q] = v2.w;
    Qt[dg + 12][q] = v3.x; Qt[dg + 13][q] = v3.y; Qt[dg + 14][q] = v3.z; Qt[dg + 15][q] = v3.w;
  }
  float m_i[4] = {-1e30f, -1e30f, -1e30f, -1e30f};
  float l_i[4] = {0.f, 0.f, 0.f, 0.f};
  float accO[4][4] = {};

  for (int c0 = 0; c0 < SEQ; c0 += 64) {
    {  // stage K^T and V (swizzled)
      const int kq = tid >> 2, dg = (tid & 3) * 16;
      const float* ks = base + 1024 + (size_t)(c0 + kq) * 3072 + dg;
      float4 k0 = ((const float4*)ks)[0];
      float4 k1 = ((const float4*)ks)[1];
      float4 k2 = ((const float4*)ks)[2];
      float4 k3 = ((const float4*)ks)[3];
      Kt[dg + 0][kq] = k0.x; Kt[dg + 1][kq] = k0.y; Kt[dg + 2][kq] = k0.z; Kt[dg + 3][kq] = k0.w;
      Kt[dg + 4][kq] = k1.x; Kt[dg + 5][kq] = k1.y; Kt[dg + 6][kq] = k1.z; Kt[dg + 7][kq] = k1.w;
      Kt[dg + 8][kq] = k2.x; Kt[dg + 9][kq] = k2.y; Kt[dg + 10][kq] = k2.z; Kt[dg + 11][kq] = k2.w;
      Kt[dg + 12][kq] = k3.x; Kt[dg + 13][kq] = k3.y; Kt[dg + 14][kq] = k3.z; Kt[dg + 15][kq] = k3.w;
      const float* vs = base + 2048 + (size_t)(c0 + kq) * 3072 + dg;
      float4 w0 = ((const float4*)vs)[0];
      float4 w1 = ((const float4*)vs)[1];
      float4 w2 = ((const float4*)vs)[2];
      float4 w3 = ((const float4*)vs)[3];
      const int dq = dg >> 2, kx = kq & 15;
      *(float4*)&Vs[kq][(((dq + 0) ^ kx) & 15) * 4] = w0;
      *(float4*)&Vs[kq][(((dq + 1) ^ kx) & 15) * 4] = w1;
      *(float4*)&Vs[kq][(((dq + 2) ^ kx) & 15) * 4] = w2;
      *(float4*)&Vs[kq][(((dq + 3) ^ kx) & 15) * 4] = w3;
    }
    __syncthreads();
    // scores S[4q][4k] for this thread
    float s[4][4] = {};
#pragma unroll 4
    for (int d = 0; d < 64; ++d) {
      const float4 qv = *(const float4*)&Qt[d][qr * 4];
      const float4 kv = *(const float4*)&Kt[d][qc * 4];
      s[0][0] = fmaf(qv.x, kv.x, s[0][0]); s[0][1] = fmaf(qv.x, kv.y, s[0][1]);
      s[0][2] = fmaf(qv.x, kv.z, s[0][2]); s[0][3] = fmaf(qv.x, kv.w, s[0][3]);
      s[1][0] = fmaf(qv.y, kv.x, s[1][0]); s[1][1] = fmaf(qv.y, kv.y, s[1][1]);
      s[1][2] = fmaf(qv.y, kv.z, s[1][2]); s[1][3] = fmaf(qv.y, kv.w, s[1][3]);
      s[2][0] = fmaf(qv.z, kv.x, s[2][0]); s[2][1] = fmaf(qv.z, kv.y, s[2][1]);
      s[2][2] = fmaf(qv.z, kv.z, s[2][2]); s[2][3] = fmaf(qv.z, kv.w, s[2][3]);
      s[3][0] = fmaf(qv.w, kv.x, s[3][0]); s[3][1] = fmaf(qv.w, kv.y, s[3][1]);
      s[3][2] = fmaf(qv.w, kv.z, s[3][2]); s[3][3] = fmaf(qv.w, kv.w, s[3][3]);
    }
    float al[4];
#pragma unroll
    for (int i = 0; i < 4; ++i) {
      float mx = fmaxf(fmaxf(s[i][0], s[i][1]), fmaxf(s[i][2], s[i][3]));
      mx = fmaxf(mx, __shfl_xor(mx, 1));
      mx = fmaxf(mx, __shfl_xor(mx, 2));
      mx = fmaxf(mx, __shfl_xor(mx, 4));
      mx = fmaxf(mx, __shfl_xor(mx, 8));
      const float mn = fmaxf(m_i[i], mx);
      al[i] = __expf(m_i[i] - mn);
      m_i[i] = mn;
      float r0 = __expf(s[i][0] - mn), r1 = __expf(s[i][1] - mn);
      float r2 = __expf(s[i][2] - mn), r3 = __expf(s[i][3] - mn);
      s[i][0] = r0; s[i][1] = r1; s[i][2] = r2; s[i][3] = r3;
      float rs = r0 + r1 + r2 + r3;
      rs += __shfl_xor(rs, 1); rs += __shfl_xor(rs, 2);
      rs += __shfl_xor(rs, 4); rs += __shfl_xor(rs, 8);
      l_i[i] = l_i[i] * al[i] + rs;
    }
#pragma unroll
    for (int i = 0; i < 4; ++i)
#pragma unroll
      for (int j = 0; j < 4; ++j) {
        const int k = qc * 4 + j;
        Pt[k][((qr ^ (k & 15)) & 15) * 4 + i] = s[i][j];
      }
    __syncthreads();
#pragma unroll
    for (int i = 0; i < 4; ++i) {
      accO[i][0] *= al[i]; accO[i][1] *= al[i];
      accO[i][2] *= al[i]; accO[i][3] *= al[i];
    }
#pragma unroll 4
    for (int k = 0; k < 64; ++k) {
      const float4 pv = *(const float4*)&Pt[k][((qr ^ (k & 15)) & 15) * 4];
      const float4 vv = *(const float4*)&Vs[k][((qc ^ (k & 15)) & 15) * 4];
      accO[0][0] = fmaf(pv.x, vv.x, accO[0][0]); accO[0][1] = fmaf(pv.x, vv.y, accO[0][1]);
      accO[0][2] = fmaf(pv.x, vv.z, accO[0][2]); accO[0][3] = fmaf(pv.x, vv.w, accO[0][3]);
      accO[1][0] = fmaf(pv.y, vv.x, accO[1][0]); accO[1][1] = fmaf(pv.y, vv.y, accO[1][1]);
      accO[1][2] = fmaf(pv.y, vv.z, accO[1][2]); accO[1][3] = fmaf(pv.y, vv.w, accO[1][3]);
      accO[2][0] = fmaf(pv.z, vv.x, accO[2][0]); accO[2][1] = fmaf(pv.z, vv.y, accO[2][1]);
      accO[2][2] = fmaf(pv.z, vv.z, accO[2][2]); accO[2][3] = fmaf(pv.z, vv.w, accO[2][3]);
      accO[3][0] = fmaf(pv.w, vv.x, accO[3][0]); accO[3][1] = fmaf(pv.w, vv.y, accO[3][1]);
      accO[3][2] = fmaf(pv.w, vv.z, accO[3][2]); accO[3][3] = fmaf(pv.w, vv.w, accO[3][3]);
    }
    __syncthreads();
  }
  const size_t obase = (size_t)(b * SEQ + q0 + qr * 4) * 1024 + h * 64 + qc * 4;
#pragma unroll
  for (int i = 0; i < 4; ++i) {
    const float inv = 1.0f / l_i[i];
    *(float4*)&o[obase + (size_t)i * 1024] =
        make_float4(accO[i][0] * inv, accO[i][1] * inv, accO[i][2] * inv, accO[i][3] * inv);
  }
}

// ---------------- gate: fp32 logits, softmax, top-2, me accumulation -------
__global__ __launch_bounds__(256) void gate_kernel(
    const float* __restrict__ h2, const float* __restrict__ gw,
    int* __restrict__ topi, float* __restrict__ tw, float* __restrict__ me_acc) {
  const int tid = threadIdx.x, w = tid >> 6, lane = tid & 63;
  const int t = blockIdx.x * 4 + w;
  const float* xr = h2 + (size_t)t * 1024;
  float acc[8] = {0.f, 0.f, 0.f, 0.f, 0.f, 0.f, 0.f, 0.f};
#pragma unroll
  for (int i = 0; i < 16; ++i) {
    const int d = lane + i * 64;
    const float xv = xr[d];
    const float4 g0 = ((const float4*)(gw + (size_t)d * 8))[0];
    const float4 g1 = ((const float4*)(gw + (size_t)d * 8))[1];
    acc[0] = fmaf(xv, g0.x, acc[0]); acc[1] = fmaf(xv, g0.y, acc[1]);
    acc[2] = fmaf(xv, g0.z, acc[2]); acc[3] = fmaf(xv, g0.w, acc[3]);
    acc[4] = fmaf(xv, g1.x, acc[4]); acc[5] = fmaf(xv, g1.y, acc[5]);
    acc[6] = fmaf(xv, g1.z, acc[6]); acc[7] = fmaf(xv, g1.w, acc[7]);
  }
#pragma unroll
  for (int e = 0; e < 8; ++e) {
    float v = acc[e];
    v += __shfl_xor(v, 1); v += __shfl_xor(v, 2); v += __shfl_xor(v, 4);
    v += __shfl_xor(v, 8); v += __shfl_xor(v, 16); v += __shfl_xor(v, 32);
    acc[e] = v;
  }
  if (lane == 0) {
    float mx = acc[0];
#pragma unroll
    for (int e = 1; e < 8; ++e) mx = fmaxf(mx, acc[e]);
    float ex[8], ssum = 0.f;
#pragma unroll
    for (int e = 0; e < 8; ++e) { ex[e] = __expf(acc[e] - mx); ssum += ex[e]; }
    const float inv = 1.f / ssum;
    float p[8];
#pragma unroll
    for (int e = 0; e < 8; ++e) p[e] = ex[e] * inv;
    int i1 = 0; float v1 = p[0];
#pragma unroll
    for (int e = 1; e < 8; ++e) if (p[e] > v1) { v1 = p[e]; i1 = e; }
    int i2 = (i1 == 0) ? 1 : 0; float v2 = p[i2];
#pragma unroll
    for (int e = 0; e < 8; ++e) if (e != i1 && p[e] > v2) { v2 = p[e]; i2 = e; }
    const float wn = 1.f / (v1 + v2);
    topi[t] = i1; topi[T_TOKENS + t] = i2;
    tw[t] = v1 * wn; tw[T_TOKENS + t] = v2 * wn;
#pragma unroll
    for (int e = 0; e < 8; ++e) atomicAdd(&me_acc[e], p[e]);
  }
}

// ---------------- routing: stable per-expert rank in k-major order ---------
__global__ __launch_bounds__(256) void route_kernel(
    const int* __restrict__ topi, int* __restrict__ pos,
    const float* __restrict__ me_acc, float* __restrict__ aux_out) {
  __shared__ int cnt[256][8];
  __shared__ int tot[8];
  const int tid = threadIdx.x;
  int lc[8] = {0, 0, 0, 0, 0, 0, 0, 0};
  const int i0 = tid * 32;
  for (int j = 0; j < 32; ++j) lc[topi[i0 + j]]++;
#pragma unroll
  for (int e = 0; e < 8; ++e) cnt[tid][e] = lc[e];
  __syncthreads();
  if (tid < 8) {
    int run = 0;
    for (int j = 0; j < 256; ++j) {
      const int v = cnt[j][tid];
      cnt[j][tid] = run;
      run += v;
    }
    tot[tid] = run;
  }
  __syncthreads();
  int base[8];
#pragma unroll
  for (int e = 0; e < 8; ++e) base[e] = cnt[tid][e];
  for (int j = 0; j < 32; ++j) {
    const int e = topi[i0 + j];
    pos[i0 + j] = base[e]++;
  }
  if (tid == 0) {
    float aux = 0.f;
    for (int e = 0; e < 8; ++e) {
      const float me = me_acc[e] / 4096.0f;
      const float ce = (float)tot[e] / (4096.0f * 2.0f);
      aux += me * ce;
    }
    aux_out[0] = 8.0f * aux;
  }
}

// ---------------- scatter tokens to expert buffers (bf16) ------------------
__global__ __launch_bounds__(128) void moe_scatter(
    const u16* __restrict__ h2b, const int* __restrict__ topi,
    const int* __restrict__ pos, u16* __restrict__ buf) {
  const int i = blockIdx.x;
  const int p = pos[i];
  if (p >= CAPACITY) return;
  const int e = topi[i];
  const int t = i & (T_TOKENS - 1);
  const uint4* src = (const uint4*)(h2b + (size_t)t * 1024);
  uint4* dst = (uint4*)(buf + ((size_t)e * CAPACITY + p) * 1024);
  dst[threadIdx.x] = src[threadIdx.x];
}

// ---------------- fp32 -> bf16 transposing converter (batched) -------------
__global__ __launch_bounds__(256) void transpose_f32_bf16(
    const float* __restrict__ in, u16* __restrict__ out, int R, int C, long sz) {
  const float* ip = in + (size_t)blockIdx.z * sz;
  u16* op = out + (size_t)blockIdx.z * sz;
  __shared__ float tile[32][33];
  const int c0 = blockIdx.x * 32, r0 = blockIdx.y * 32;
  const int tx = threadIdx.x & 31, ty = threadIdx.x >> 5;
#pragma unroll
  for (int i = 0; i < 32; i += 8)
    tile[ty + i][tx] = ip[(size_t)(r0 + ty + i) * C + c0 + tx];
  __syncthreads();
#pragma unroll
  for (int i = 0; i < 32; i += 8)
    op[(size_t)(c0 + ty + i) * R + r0 + tx] = f2bf(tile[tx][ty + i]);
}

// ---------------- bf16 MFMA GEMM: C = A[M,K] @ BT[N,K]^T + bias ------------
// EPI 0: bf16 out. EPI 1: bf16 gelu(out).
template <int EPI>
__global__ __launch_bounds__(256, 2) void bgemm_bt(
    const u16* __restrict__ Ab, const u16* __restrict__ BTb,
    const float* __restrict__ biasb, u16* __restrict__ Cb,
    int M, int N, int K, long sA, long sB, long sBias, long sC) {
  const int e = blockIdx.z;
  const u16* A = Ab + (size_t)e * sA;
  const u16* BT = BTb + (size_t)e * sB;
  const float* bias = biasb + (size_t)e * sBias;
  u16* C = Cb + (size_t)e * sC;

  __shared__ u16 As[128 * 40];  // stride 40 (+8 pad): frag reads 2-way = free
  __shared__ u16 Bs[128 * 40];
  const int tid = threadIdx.x, lane = tid & 63, w = tid >> 6;
  const int qd = lane >> 4, ml = lane & 15;
  const int m0 = blockIdx.y * 128, n0 = blockIdx.x * 128;
  const int wm = (w & 1) * 64, wn = (w >> 1) * 64;
  f32x4 acc[4][4] = {};

  const int sr = tid >> 1, sh = (tid & 1) * 16;
  const u16* gA = A + (size_t)(m0 + sr) * K + sh;
  const u16* gB = BT + (size_t)(n0 + sr) * K + sh;
  u16* lA = &As[sr * 40 + sh];
  u16* lB = &Bs[sr * 40 + sh];

  for (int k0 = 0; k0 < K; k0 += 32) {
    const uint4 av0 = *(const uint4*)(gA + k0);
    const uint4 av1 = *(const uint4*)(gA + k0 + 8);
    const uint4 bv0 = *(const uint4*)(gB + k0);
    const uint4 bv1 = *(const uint4*)(gB + k0 + 8);
    __syncthreads();
    *(uint4*)lA = av0; *(uint4*)(lA + 8) = av1;
    *(uint4*)lB = bv0; *(uint4*)(lB + 8) = bv1;
    __syncthreads();
    bf16x8 af[4], bfr[4];
#pragma unroll
    for (int i = 0; i < 4; ++i)
      af[i] = *(const bf16x8*)&As[(wm + i * 16 + ml) * 40 + qd * 8];
#pragma unroll
    for (int j = 0; j < 4; ++j)
      bfr[j] = *(const bf16x8*)&Bs[(wn + j * 16 + ml) * 40 + qd * 8];
#pragma unroll
    for (int i = 0; i < 4; ++i)
#pragma unroll
      for (int j = 0; j < 4; ++j)
        acc[i][j] = __builtin_amdgcn_mfma_f32_16x16x32_bf16(af[i], bfr[j], acc[i][j], 0, 0, 0);
  }
#pragma unroll
  for (int i = 0; i < 4; ++i) {
    const int rr = m0 + wm + i * 16 + qd * 4;
#pragma unroll
    for (int j = 0; j < 4; ++j) {
      const int cc = n0 + wn + j * 16 + ml;
      const float bb = bias[cc];
#pragma unroll
      for (int p = 0; p < 4; ++p) {
        float v = acc[i][j][p] + bb;
        if (EPI == 1) v = gelu_f(v);
        C[(size_t)(rr + p) * N + cc] = f2bf(v);
      }
    }
  }
}

// ---------------- gather expert outputs back + final residual add ----------
__global__ __launch_bounds__(256) void moe_gather(
    const u16* __restrict__ outm, const int* __restrict__ topi,
    const int* __restrict__ pos, const float* __restrict__ tw,
    float* __restrict__ y) {
  const int t = blockIdx.x;
  const int d = threadIdx.x * 4;
  float a0 = 0.f, a1 = 0.f, a2 = 0.f, a3 = 0.f;
#pragma unroll
  for (int k = 0; k < 2; ++k) {
    const int i = k * T_TOKENS + t;
    const int p = pos[i];
    if (p < CAPACITY) {
      const int e = topi[i];
      const float wg = tw[i];
      const ushort4 r = *(const ushort4*)(outm + ((size_t)e * CAPACITY + p) * 1024 + d);
      a0 = fmaf(wg, bf2f(r.x), a0);
      a1 = fmaf(wg, bf2f(r.y), a1);
      a2 = fmaf(wg, bf2f(r.z), a2);
      a3 = fmaf(wg, bf2f(r.w), a3);
    }
  }
  float4* op = (float4*)(y + (size_t)t * 1024 + d);
  float4 cur = *op;
  cur.x += a0; cur.y += a1; cur.z += a2; cur.w += a3;
  *op = cur;
}

// ---------------- workspace layout ----------------------------------------
static const size_t OFF_STATS = 0;                       // me_acc 32B
static const size_t OFF_TOPI = 0x100;                    // 8192 i32
static const size_t OFF_TW = 0x8100;                     // 8192 f32
static const size_t OFF_POS = 0x10100;                   // 8192 i32
static const size_t OFF_H = 0x20000;                     // 16MB f32 (h, then attn o)
static const size_t OFF_QKV = OFF_H + 0x1000000;         // 48MB f32 (qkv; later outm+h2f)
static const size_t OFF_H2F = OFF_QKV + 0x1400000;       // 16MB f32 (inside qkv region)
static const size_t OFF_H2B = OFF_QKV + 0x3000000;       // 8MB bf16
static const size_t OFF_BUF = OFF_H2B + 0x800000;        // 20MB bf16
static const size_t OFF_WT = OFF_BUF + 0x1400000;        // 64MB bf16 (w1t then w2t)
static const size_t OFF_HH = OFF_WT + 0x4000000;         // 80MB bf16
static const size_t WS_NEED = OFF_HH + 0x5000000;        // ~236 MB

extern "C" void kernel_launch(void* const* d_in, const int* in_sizes, int n_in,
                              void* d_out, int out_size, void* d_ws, size_t ws_size,
                              hipStream_t stream) {
  (void)in_sizes; (void)n_in; (void)out_size;
  if (ws_size < WS_NEED) return;  // fail visibly rather than corrupt

  const float* x = (const float*)d_in[0];
  const float* cosb = (const float*)d_in[1];
  const float* sinb = (const float*)d_in[2];
  const float* ln1g = (const float*)d_in[3];
  const float* ln1b = (const float*)d_in[4];
  const float* ln2g = (const float*)d_in[5];
  const float* ln2b = (const float*)d_in[6];
  const float* wqkv = (const float*)d_in[7];
  const float* bqkv = (const float*)d_in[8];
  const float* wo = (const float*)d_in[9];
  const float* bo = (const float*)d_in[10];
  const float* gatew = (const float*)d_in[11];
  const float* w1 = (const float*)d_in[12];
  const float* b1 = (const float*)d_in[13];
  const float* w2 = (const float*)d_in[14];
  const float* b2 = (const float*)d_in[15];
  float* out = (float*)d_out;

  char* ws = (char*)d_ws;
  float* me_acc = (float*)(ws + OFF_STATS);
  int* topi = (int*)(ws + OFF_TOPI);
  float* tw = (float*)(ws + OFF_TW);
  int* pos = (int*)(ws + OFF_POS);
  float* h = (float*)(ws + OFF_H);
  float* o = (float*)(ws + OFF_H);      // reuse (h dead after QKV GEMM)
  float* qkv = (float*)(ws + OFF_QKV);
  u16* outm = (u16*)(ws + OFF_QKV);     // reuse (qkv dead after attention)
  float* h2f = (float*)(ws + OFF_H2F);
  u16* h2b = (u16*)(ws + OFF_H2B);
  u16* buf = (u16*)(ws + OFF_BUF);
  u16* wt = (u16*)(ws + OFF_WT);
  u16* hh = (u16*)(ws + OFF_HH);

  hipMemsetAsync(me_acc, 0, 64, stream);
  hipMemsetAsync(buf, 0, (size_t)8 * CAPACITY * 1024 * 2, stream);

  // pre-gate path: fp32 end-to-end (routing exactness)
  ln_kernel<<<4096, 256, 0, stream>>>(x, ln1g, ln1b, h, (u16*)nullptr);
  sgemm<0><<<dim3(24, 32, 1), 256, 0, stream>>>(h, wqkv, bqkv, nullptr, qkv, 4096, 3072, 1024);
  rope_kernel<<<4096, 256, 0, stream>>>(qkv, cosb, sinb);
  attn_f32<<<dim3(32, 32, 1), 256, 0, stream>>>(qkv, o);
  sgemm<1><<<dim3(8, 32, 1), 256, 0, stream>>>(o, wo, bo, x, out, 4096, 1024, 1024);
  ln_kernel<<<4096, 256, 0, stream>>>(out, ln2g, ln2b, h2f, h2b);
  gate_kernel<<<1024, 256, 0, stream>>>(h2f, gatew, topi, tw, me_acc);
  route_kernel<<<1, 256, 0, stream>>>(topi, pos, me_acc, out + 4194304);

  // MoE experts: bf16 MFMA (smooth path)
  moe_scatter<<<8192, 128, 0, stream>>>(h2b, topi, pos, buf);
  transpose_f32_bf16<<<dim3(128, 32, 8), 256, 0, stream>>>(w1, wt, 1024, 4096, 1024L * 4096);
  bgemm_bt<1><<<dim3(32, 10, 8), 256, 0, stream>>>(buf, wt, b1, hh, 1280, 4096, 1024,
                                                   1280L * 1024, 4096L * 1024, 4096, 1280L * 4096);
  transpose_f32_bf16<<<dim3(32, 128, 8), 256, 0, stream>>>(w2, wt, 4096, 1024, 4096L * 1024);
  bgemm_bt<0><<<dim3(8, 10, 8), 256, 0, stream>>>(hh, wt, b2, outm, 1280, 1024, 4096,
                                                  1280L * 4096, 1024L * 4096, 1024, 1280L * 1024);
  moe_gather<<<4096, 256, 0, stream>>>(outm, topi, pos, tw, out);
}

// Round 2
// 1488.773 us; speedup vs baseline: 1.4539x; 1.4539x over previous
//
#include <hip/hip_runtime.h>

// Round 2: pre-gate path moved from fp32 VALU to split-fp16 (hi+lo) MFMA,
// 3 passes per product (AhBh + AhBl + AlBh) -> rel err ~2.4e-7, far below
// the ~1e-4 min top-2/3 gate gap, so routing stays exact vs the fp32 ref.
// Experts stay bf16 MFMA (smooth path).

typedef unsigned short u16;
typedef short bf16x8 __attribute__((ext_vector_type(8)));
typedef float f32x4 __attribute__((ext_vector_type(4)));
typedef _Float16 f16;
typedef f16 f16x8 __attribute__((ext_vector_type(8)));
typedef f16 f16x4 __attribute__((ext_vector_type(4)));

#define T_TOKENS 4096
#define SEQ      2048
#define CAPACITY 1280

__device__ __forceinline__ u16 f2bf(float f) {
  unsigned int u = __float_as_uint(f);
  return (u16)((u + 0x7FFFu + ((u >> 16) & 1u)) >> 16);
}
__device__ __forceinline__ float bf2f(u16 h) {
  return __uint_as_float(((unsigned int)h) << 16);
}
__device__ __forceinline__ float gelu_f(float x) {
  float x3 = x * x * x;
  float t = tanhf(0.7978845608028654f * (x + 0.044715f * x3));
  return 0.5f * x * (1.0f + t);
}

// ---------------- LayerNorm (fp32 in, fp32 and/or bf16 out) ----------------
__global__ __launch_bounds__(256) void ln_kernel(
    const float* __restrict__ x, const float* __restrict__ g,
    const float* __restrict__ bt, float* __restrict__ of32,
    u16* __restrict__ obf) {
  const int t = blockIdx.x, tid = threadIdx.x;
  float4 v = ((const float4*)(x + (size_t)t * 1024))[tid];
  float s = v.x + v.y + v.z + v.w;
  float sq = v.x * v.x + v.y * v.y + v.z * v.z + v.w * v.w;
#pragma unroll
  for (int d = 1; d < 64; d <<= 1) {
    s += __shfl_xor(s, d);
    sq += __shfl_xor(sq, d);
  }
  __shared__ float red[8];
  if ((tid & 63) == 0) { red[tid >> 6] = s; red[4 + (tid >> 6)] = sq; }
  __syncthreads();
  s = red[0] + red[1] + red[2] + red[3];
  sq = red[4] + red[5] + red[6] + red[7];
  const float mu = s * (1.0f / 1024.0f);
  const float var = sq * (1.0f / 1024.0f) - mu * mu;
  const float rs = rsqrtf(var + 1e-6f);
  float4 gv = ((const float4*)g)[tid];
  float4 bv = ((const float4*)bt)[tid];
  float4 o;
  o.x = (v.x - mu) * rs * gv.x + bv.x;
  o.y = (v.y - mu) * rs * gv.y + bv.y;
  o.z = (v.z - mu) * rs * gv.z + bv.z;
  o.w = (v.w - mu) * rs * gv.w + bv.w;
  if (of32) ((float4*)(of32 + (size_t)t * 1024))[tid] = o;
  if (obf) {
    ushort4 ob;
    ob.x = f2bf(o.x); ob.y = f2bf(o.y); ob.z = f2bf(o.z); ob.w = f2bf(o.w);
    ((ushort4*)(obf + (size_t)t * 1024))[tid] = ob;
  }
}

// ------- transpose fp32 [R][C] -> f16 hi/lo [C][R] (weight prep) ----------
__global__ __launch_bounds__(256) void transpose_f32_f16hl(
    const float* __restrict__ in, f16* __restrict__ outh, f16* __restrict__ outl,
    int R, int C) {
  __shared__ float tile[32][33];
  const int c0 = blockIdx.x * 32, r0 = blockIdx.y * 32;
  const int tx = threadIdx.x & 31, ty = threadIdx.x >> 5;
#pragma unroll
  for (int i = 0; i < 32; i += 8)
    tile[ty + i][tx] = in[(size_t)(r0 + ty + i) * C + c0 + tx];
  __syncthreads();
#pragma unroll
  for (int i = 0; i < 32; i += 8) {
    const float v = tile[tx][ty + i];
    const f16 hi = (f16)v;
    const size_t idx = (size_t)(c0 + ty + i) * R + r0 + tx;
    outh[idx] = hi;
    outl[idx] = (f16)(v - (float)hi);
  }
}

// ------- split-fp16 3-pass MFMA GEMM: C = A[M,K]@BT[N,K]^T + bias (+res) ---
// A fp32 (converted hi/lo on the fly), BT pre-split f16 hi/lo. fp32 out.
template <int EPI>
__global__ __launch_bounds__(256, 2) void gemm_f16x3_bt(
    const float* __restrict__ A, const f16* __restrict__ Bth,
    const f16* __restrict__ Btl, const float* __restrict__ bias,
    const float* __restrict__ res, float* __restrict__ C, int M, int N, int K) {
  __shared__ f16 Ah[128 * 40], Al[128 * 40], Bh[128 * 40], Bl[128 * 40];
  const int tid = threadIdx.x, lane = tid & 63, w = tid >> 6;
  const int qd = lane >> 4, ml = lane & 15;
  const int m0 = blockIdx.y * 128, n0 = blockIdx.x * 128;
  const int wm = (w & 1) * 64, wn = (w >> 1) * 64;
  f32x4 acc[4][4] = {};

  const int sr = tid >> 1, sc = (tid & 1) * 16;
  const float* gA = A + (size_t)(m0 + sr) * K + sc;
  const f16* gBh = Bth + (size_t)(n0 + sr) * K + sc;
  const f16* gBl = Btl + (size_t)(n0 + sr) * K + sc;
  f16* lAh = &Ah[sr * 40 + sc];
  f16* lAl = &Al[sr * 40 + sc];
  f16* lBh = &Bh[sr * 40 + sc];
  f16* lBl = &Bl[sr * 40 + sc];

  for (int k0 = 0; k0 < K; k0 += 32) {
    const float4 a0 = *(const float4*)(gA + k0);
    const float4 a1 = *(const float4*)(gA + k0 + 4);
    const float4 a2 = *(const float4*)(gA + k0 + 8);
    const float4 a3 = *(const float4*)(gA + k0 + 12);
    const uint4 bh0 = *(const uint4*)(gBh + k0);
    const uint4 bh1 = *(const uint4*)(gBh + k0 + 8);
    const uint4 bl0 = *(const uint4*)(gBl + k0);
    const uint4 bl1 = *(const uint4*)(gBl + k0 + 8);
    const float af[16] = {a0.x, a0.y, a0.z, a0.w, a1.x, a1.y, a1.z, a1.w,
                          a2.x, a2.y, a2.z, a2.w, a3.x, a3.y, a3.z, a3.w};
    f16x8 h0, h1, l0, l1;
#pragma unroll
    for (int ii = 0; ii < 8; ++ii) {
      f16 hi = (f16)af[ii];
      h0[ii] = hi;
      l0[ii] = (f16)(af[ii] - (float)hi);
      f16 hi2 = (f16)af[8 + ii];
      h1[ii] = hi2;
      l1[ii] = (f16)(af[8 + ii] - (float)hi2);
    }
    __syncthreads();
    *(f16x8*)lAh = h0; *(f16x8*)(lAh + 8) = h1;
    *(f16x8*)lAl = l0; *(f16x8*)(lAl + 8) = l1;
    *(uint4*)lBh = bh0; *(uint4*)(lBh + 8) = bh1;
    *(uint4*)lBl = bl0; *(uint4*)(lBl + 8) = bl1;
    __syncthreads();
    f16x8 fah[4], fal[4], fbh[4], fbl[4];
#pragma unroll
    for (int i = 0; i < 4; ++i) {
      fah[i] = *(const f16x8*)&Ah[(wm + i * 16 + ml) * 40 + qd * 8];
      fal[i] = *(const f16x8*)&Al[(wm + i * 16 + ml) * 40 + qd * 8];
    }
#pragma unroll
    for (int j = 0; j < 4; ++j) {
      fbh[j] = *(const f16x8*)&Bh[(wn + j * 16 + ml) * 40 + qd * 8];
      fbl[j] = *(const f16x8*)&Bl[(wn + j * 16 + ml) * 40 + qd * 8];
    }
#pragma unroll
    for (int i = 0; i < 4; ++i)
#pragma unroll
      for (int j = 0; j < 4; ++j) {
        acc[i][j] = __builtin_amdgcn_mfma_f32_16x16x32_f16(fah[i], fbh[j], acc[i][j], 0, 0, 0);
        acc[i][j] = __builtin_amdgcn_mfma_f32_16x16x32_f16(fah[i], fbl[j], acc[i][j], 0, 0, 0);
        acc[i][j] = __builtin_amdgcn_mfma_f32_16x16x32_f16(fal[i], fbh[j], acc[i][j], 0, 0, 0);
      }
  }
#pragma unroll
  for (int i = 0; i < 4; ++i) {
    const int rr = m0 + wm + i * 16 + qd * 4;
#pragma unroll
    for (int j = 0; j < 4; ++j) {
      const int cc = n0 + wn + j * 16 + ml;
      const float bb = bias[cc];
#pragma unroll
      for (int p = 0; p < 4; ++p) {
        float v = acc[i][j][p] + bb;
        if (EPI == 1) v += res[(size_t)(rr + p) * N + cc];
        C[(size_t)(rr + p) * N + cc] = v;
      }
    }
  }
}

// ---------------- RoPE (in-place on fp32 qkv, q pre-scaled by 1/8) ---------
__global__ __launch_bounds__(256) void rope_kernel(
    float* __restrict__ qkv, const float* __restrict__ cosb,
    const float* __restrict__ sinb) {
  const int t = blockIdx.x;
  const int s = t & (SEQ - 1);
  float* row = qkv + (size_t)t * 3072;
  const int tid = threadIdx.x;
#pragma unroll
  for (int it = 0; it < 4; ++it) {
    const int p = tid + it * 256;           // 1024 pairs
    const int sec = p >> 9;                 // 0=q, 1=k
    const int rem = p & 511;
    const int h = rem >> 5, d = rem & 31;
    const int col = sec * 1024 + h * 64 + d;
    const float c1 = cosb[s * 64 + d], s1 = sinb[s * 64 + d];
    const float c2 = cosb[s * 64 + d + 32], s2 = sinb[s * 64 + d + 32];
    const float a = row[col], b = row[col + 32];
    float na = a * c1 - b * s1;
    float nb = b * c2 + a * s2;
    if (sec == 0) { na *= 0.125f; nb *= 0.125f; }
    row[col] = na;
    row[col + 32] = nb;
  }
}

// ---------------- split-fp16 MFMA flash attention --------------------------
// grid (S/64, B*H), 256 thr. 64 q-rows/block (16 per wave), 64-key chunks.
// QK^T and PV each 3-pass split-fp16. LDS 54 KiB -> 2 blocks/CU.
__global__ __launch_bounds__(256) void attn_mfma(
    const float* __restrict__ qkv, float* __restrict__ o) {
  const int bh = blockIdx.y, b = bh >> 4, h = bh & 15;
  const int tid = threadIdx.x, w = tid >> 6, lane = tid & 63;
  const int quad = lane >> 4, ml = lane & 15;
  const int q0 = blockIdx.x * 64;
  const float* base = qkv + (size_t)b * SEQ * 3072 + h * 64;

  __shared__ f16 Kh[64 * 72], Kl[64 * 72];  // [key][d]   (B-frag for QK)
  __shared__ f16 Vh[64 * 72], Vl[64 * 72];  // [d][key]   (B-frag for PV)
  __shared__ f16 Ph[64 * 72], Pl[64 * 72];  // [q][key]   (A-frag for PV)

  // Q fragments (A-layout: m=lane&15, k=quad*8+j), rope already scaled q/8
  f16x8 qh[2], ql[2];
  {
    const float* qrow = base + (size_t)(q0 + w * 16 + ml) * 3072;
#pragma unroll
    for (int ks = 0; ks < 2; ++ks) {
      const float4 a = *(const float4*)(qrow + ks * 32 + quad * 8);
      const float4 c = *(const float4*)(qrow + ks * 32 + quad * 8 + 4);
      const float f[8] = {a.x, a.y, a.z, a.w, c.x, c.y, c.z, c.w};
#pragma unroll
      for (int ii = 0; ii < 8; ++ii) {
        f16 hi = (f16)f[ii];
        qh[ks][ii] = hi;
        ql[ks][ii] = (f16)(f[ii] - (float)hi);
      }
    }
  }

  float m_i[4] = {-1e30f, -1e30f, -1e30f, -1e30f};
  float l_i[4] = {0.f, 0.f, 0.f, 0.f};
  f32x4 accO[4] = {};  // [d-tile]; row = quad*4+p

  const int skey = tid >> 2, scg = (tid & 3) * 16;   // K staging
  const int sd0 = (tid & 15) * 4, sk0 = (tid >> 4) * 4;  // V staging

  for (int c0 = 0; c0 < SEQ; c0 += 64) {
    __syncthreads();
    {  // stage K (hi/lo) and V^T (hi/lo)
      const float* kr = base + 1024 + (size_t)(c0 + skey) * 3072 + scg;
      const float4 r0 = ((const float4*)kr)[0];
      const float4 r1 = ((const float4*)kr)[1];
      const float4 r2 = ((const float4*)kr)[2];
      const float4 r3 = ((const float4*)kr)[3];
      const float kf[16] = {r0.x, r0.y, r0.z, r0.w, r1.x, r1.y, r1.z, r1.w,
                            r2.x, r2.y, r2.z, r2.w, r3.x, r3.y, r3.z, r3.w};
      f16x8 h0, h1, l0, l1;
#pragma unroll
      for (int ii = 0; ii < 8; ++ii) {
        f16 hi = (f16)kf[ii];
        h0[ii] = hi;
        l0[ii] = (f16)(kf[ii] - (float)hi);
        f16 hi2 = (f16)kf[8 + ii];
        h1[ii] = hi2;
        l1[ii] = (f16)(kf[8 + ii] - (float)hi2);
      }
      *(f16x8*)&Kh[skey * 72 + scg] = h0;
      *(f16x8*)&Kh[skey * 72 + scg + 8] = h1;
      *(f16x8*)&Kl[skey * 72 + scg] = l0;
      *(f16x8*)&Kl[skey * 72 + scg + 8] = l1;

      float4 rv[4];
#pragma unroll
      for (int i = 0; i < 4; ++i)
        rv[i] = *(const float4*)(base + 2048 + (size_t)(c0 + sk0 + i) * 3072 + sd0);
#pragma unroll
      for (int dd = 0; dd < 4; ++dd) {
        f16x4 vh4, vl4;
#pragma unroll
        for (int i = 0; i < 4; ++i) {
          const float fv = ((const float*)&rv[i])[dd];
          f16 hi = (f16)fv;
          vh4[i] = hi;
          vl4[i] = (f16)(fv - (float)hi);
        }
        *(f16x4*)&Vh[(sd0 + dd) * 72 + sk0] = vh4;
        *(f16x4*)&Vl[(sd0 + dd) * 72 + sk0] = vl4;
      }
    }
    __syncthreads();

    // S = Q K^T (3-pass split-fp16)
    f32x4 s[4] = {};
#pragma unroll
    for (int ks = 0; ks < 2; ++ks)
#pragma unroll
      for (int j = 0; j < 4; ++j) {
        const f16x8 kh = *(const f16x8*)&Kh[(j * 16 + ml) * 72 + ks * 32 + quad * 8];
        const f16x8 kl = *(const f16x8*)&Kl[(j * 16 + ml) * 72 + ks * 32 + quad * 8];
        s[j] = __builtin_amdgcn_mfma_f32_16x16x32_f16(qh[ks], kh, s[j], 0, 0, 0);
        s[j] = __builtin_amdgcn_mfma_f32_16x16x32_f16(qh[ks], kl, s[j], 0, 0, 0);
        s[j] = __builtin_amdgcn_mfma_f32_16x16x32_f16(ql[ks], kh, s[j], 0, 0, 0);
      }

    // online softmax per row p (row = quad*4+p); reduce across 16-lane group
    float alpha[4];
#pragma unroll
    for (int p = 0; p < 4; ++p) {
      float mx = fmaxf(fmaxf(s[0][p], s[1][p]), fmaxf(s[2][p], s[3][p]));
      mx = fmaxf(mx, __shfl_xor(mx, 1));
      mx = fmaxf(mx, __shfl_xor(mx, 2));
      mx = fmaxf(mx, __shfl_xor(mx, 4));
      mx = fmaxf(mx, __shfl_xor(mx, 8));
      const float mn = fmaxf(m_i[p], mx);
      const float al = __expf(m_i[p] - mn);
      float rs = 0.f;
#pragma unroll
      for (int j = 0; j < 4; ++j) {
        const float e = __expf(s[j][p] - mn);
        s[j][p] = e;
        rs += e;
      }
      rs += __shfl_xor(rs, 1);
      rs += __shfl_xor(rs, 2);
      rs += __shfl_xor(rs, 4);
      rs += __shfl_xor(rs, 8);
      m_i[p] = mn;
      l_i[p] = l_i[p] * al + rs;
      alpha[p] = al;
    }
#pragma unroll
    for (int j = 0; j < 4; ++j)
#pragma unroll
      for (int p = 0; p < 4; ++p) accO[j][p] *= alpha[p];

    // P -> LDS (per-wave rows; hi/lo split). Same-wave RAW, no barrier.
#pragma unroll
    for (int j = 0; j < 4; ++j)
#pragma unroll
      for (int p = 0; p < 4; ++p) {
        const float v = s[j][p];
        const f16 hi = (f16)v;
        const int row = w * 16 + quad * 4 + p, col = ml + 16 * j;
        Ph[row * 72 + col] = hi;
        Pl[row * 72 + col] = (f16)(v - (float)hi);
      }

    // O += P V (3-pass split-fp16)
#pragma unroll
    for (int ks = 0; ks < 2; ++ks) {
      const f16x8 pah = *(const f16x8*)&Ph[(w * 16 + ml) * 72 + ks * 32 + quad * 8];
      const f16x8 pal = *(const f16x8*)&Pl[(w * 16 + ml) * 72 + ks * 32 + quad * 8];
#pragma unroll
      for (int j = 0; j < 4; ++j) {
        const f16x8 vbh = *(const f16x8*)&Vh[(j * 16 + ml) * 72 + ks * 32 + quad * 8];
        const f16x8 vbl = *(const f16x8*)&Vl[(j * 16 + ml) * 72 + ks * 32 + quad * 8];
        accO[j] = __builtin_amdgcn_mfma_f32_16x16x32_f16(pah, vbh, accO[j], 0, 0, 0);
        accO[j] = __builtin_amdgcn_mfma_f32_16x16x32_f16(pah, vbl, accO[j], 0, 0, 0);
        accO[j] = __builtin_amdgcn_mfma_f32_16x16x32_f16(pal, vbh, accO[j], 0, 0, 0);
      }
    }
  }
  // epilogue: rows quad*4+p, cols h*64 + j*16 + ml
  const int trow = q0 + w * 16 + quad * 4;
#pragma unroll
  for (int p = 0; p < 4; ++p) {
    const float inv = 1.0f / l_i[p];
    const size_t ob = (size_t)(b * SEQ + trow + p) * 1024 + h * 64 + ml;
#pragma unroll
    for (int j = 0; j < 4; ++j) o[ob + j * 16] = accO[j][p] * inv;
  }
}

// ---------------- gate: fp32 logits, softmax, top-2, me accumulation -------
__global__ __launch_bounds__(256) void gate_kernel(
    const float* __restrict__ h2, const float* __restrict__ gw,
    int* __restrict__ topi, float* __restrict__ tw, float* __restrict__ me_acc) {
  const int tid = threadIdx.x, w = tid >> 6, lane = tid & 63;
  const int t = blockIdx.x * 4 + w;
  const float* xr = h2 + (size_t)t * 1024;
  float acc[8] = {0.f, 0.f, 0.f, 0.f, 0.f, 0.f, 0.f, 0.f};
#pragma unroll
  for (int i = 0; i < 16; ++i) {
    const int d = lane + i * 64;
    const float xv = xr[d];
    const float4 g0 = ((const float4*)(gw + (size_t)d * 8))[0];
    const float4 g1 = ((const float4*)(gw + (size_t)d * 8))[1];
    acc[0] = fmaf(xv, g0.x, acc[0]); acc[1] = fmaf(xv, g0.y, acc[1]);
    acc[2] = fmaf(xv, g0.z, acc[2]); acc[3] = fmaf(xv, g0.w, acc[3]);
    acc[4] = fmaf(xv, g1.x, acc[4]); acc[5] = fmaf(xv, g1.y, acc[5]);
    acc[6] = fmaf(xv, g1.z, acc[6]); acc[7] = fmaf(xv, g1.w, acc[7]);
  }
#pragma unroll
  for (int e = 0; e < 8; ++e) {
    float v = acc[e];
    v += __shfl_xor(v, 1); v += __shfl_xor(v, 2); v += __shfl_xor(v, 4);
    v += __shfl_xor(v, 8); v += __shfl_xor(v, 16); v += __shfl_xor(v, 32);
    acc[e] = v;
  }
  if (lane == 0) {
    float mx = acc[0];
#pragma unroll
    for (int e = 1; e < 8; ++e) mx = fmaxf(mx, acc[e]);
    float ex[8], ssum = 0.f;
#pragma unroll
    for (int e = 0; e < 8; ++e) { ex[e] = __expf(acc[e] - mx); ssum += ex[e]; }
    const float inv = 1.f / ssum;
    float p[8];
#pragma unroll
    for (int e = 0; e < 8; ++e) p[e] = ex[e] * inv;
    int i1 = 0; float v1 = p[0];
#pragma unroll
    for (int e = 1; e < 8; ++e) if (p[e] > v1) { v1 = p[e]; i1 = e; }
    int i2 = (i1 == 0) ? 1 : 0; float v2 = p[i2];
#pragma unroll
    for (int e = 0; e < 8; ++e) if (e != i1 && p[e] > v2) { v2 = p[e]; i2 = e; }
    const float wn = 1.f / (v1 + v2);
    topi[t] = i1; topi[T_TOKENS + t] = i2;
    tw[t] = v1 * wn; tw[T_TOKENS + t] = v2 * wn;
#pragma unroll
    for (int e = 0; e < 8; ++e) atomicAdd(&me_acc[e], p[e]);
  }
}

// ---------------- routing: stable per-expert rank in k-major order ---------
__global__ __launch_bounds__(256) void route_kernel(
    const int* __restrict__ topi, int* __restrict__ pos,
    const float* __restrict__ me_acc, float* __restrict__ aux_out) {
  __shared__ int cnt[256][8];
  __shared__ int tot[8];
  const int tid = threadIdx.x;
  int lc[8] = {0, 0, 0, 0, 0, 0, 0, 0};
  const int i0 = tid * 32;
  for (int j = 0; j < 32; ++j) lc[topi[i0 + j]]++;
#pragma unroll
  for (int e = 0; e < 8; ++e) cnt[tid][e] = lc[e];
  __syncthreads();
  if (tid < 8) {
    int run = 0;
    for (int j = 0; j < 256; ++j) {
      const int v = cnt[j][tid];
      cnt[j][tid] = run;
      run += v;
    }
    tot[tid] = run;
  }
  __syncthreads();
  int base[8];
#pragma unroll
  for (int e = 0; e < 8; ++e) base[e] = cnt[tid][e];
  for (int j = 0; j < 32; ++j) {
    const int e = topi[i0 + j];
    pos[i0 + j] = base[e]++;
  }
  if (tid == 0) {
    float aux = 0.f;
    for (int e = 0; e < 8; ++e) {
      const float me = me_acc[e] / 4096.0f;
      const float ce = (float)tot[e] / (4096.0f * 2.0f);
      aux += me * ce;
    }
    aux_out[0] = 8.0f * aux;
  }
}

// ---------------- scatter tokens to expert buffers (bf16) ------------------
__global__ __launch_bounds__(128) void moe_scatter(
    const u16* __restrict__ h2b, const int* __restrict__ topi,
    const int* __restrict__ pos, u16* __restrict__ buf) {
  const int i = blockIdx.x;
  const int p = pos[i];
  if (p >= CAPACITY) return;
  const int e = topi[i];
  const int t = i & (T_TOKENS - 1);
  const uint4* src = (const uint4*)(h2b + (size_t)t * 1024);
  uint4* dst = (uint4*)(buf + ((size_t)e * CAPACITY + p) * 1024);
  dst[threadIdx.x] = src[threadIdx.x];
}

// ---------------- fp32 -> bf16 transposing converter (batched) -------------
__global__ __launch_bounds__(256) void transpose_f32_bf16(
    const float* __restrict__ in, u16* __restrict__ out, int R, int C, long sz) {
  const float* ip = in + (size_t)blockIdx.z * sz;
  u16* op = out + (size_t)blockIdx.z * sz;
  __shared__ float tile[32][33];
  const int c0 = blockIdx.x * 32, r0 = blockIdx.y * 32;
  const int tx = threadIdx.x & 31, ty = threadIdx.x >> 5;
#pragma unroll
  for (int i = 0; i < 32; i += 8)
    tile[ty + i][tx] = ip[(size_t)(r0 + ty + i) * C + c0 + tx];
  __syncthreads();
#pragma unroll
  for (int i = 0; i < 32; i += 8)
    op[(size_t)(c0 + ty + i) * R + r0 + tx] = f2bf(tile[tx][ty + i]);
}

// ---------------- bf16 MFMA GEMM: C = A[M,K] @ BT[N,K]^T + bias ------------
// EPI 0: bf16 out. EPI 1: bf16 gelu(out).
template <int EPI>
__global__ __launch_bounds__(256, 2) void bgemm_bt(
    const u16* __restrict__ Ab, const u16* __restrict__ BTb,
    const float* __restrict__ biasb, u16* __restrict__ Cb,
    int M, int N, int K, long sA, long sB, long sBias, long sC) {
  const int e = blockIdx.z;
  const u16* A = Ab + (size_t)e * sA;
  const u16* BT = BTb + (size_t)e * sB;
  const float* bias = biasb + (size_t)e * sBias;
  u16* C = Cb + (size_t)e * sC;

  __shared__ u16 As[128 * 40];  // stride 40 (+8 pad): frag reads 2-way = free
  __shared__ u16 Bs[128 * 40];
  const int tid = threadIdx.x, lane = tid & 63, w = tid >> 6;
  const int qd = lane >> 4, ml = lane & 15;
  const int m0 = blockIdx.y * 128, n0 = blockIdx.x * 128;
  const int wm = (w & 1) * 64, wn = (w >> 1) * 64;
  f32x4 acc[4][4] = {};

  const int sr = tid >> 1, sh = (tid & 1) * 16;
  const u16* gA = A + (size_t)(m0 + sr) * K + sh;
  const u16* gB = BT + (size_t)(n0 + sr) * K + sh;
  u16* lA = &As[sr * 40 + sh];
  u16* lB = &Bs[sr * 40 + sh];

  for (int k0 = 0; k0 < K; k0 += 32) {
    const uint4 av0 = *(const uint4*)(gA + k0);
    const uint4 av1 = *(const uint4*)(gA + k0 + 8);
    const uint4 bv0 = *(const uint4*)(gB + k0);
    const uint4 bv1 = *(const uint4*)(gB + k0 + 8);
    __syncthreads();
    *(uint4*)lA = av0; *(uint4*)(lA + 8) = av1;
    *(uint4*)lB = bv0; *(uint4*)(lB + 8) = bv1;
    __syncthreads();
    bf16x8 af[4], bfr[4];
#pragma unroll
    for (int i = 0; i < 4; ++i)
      af[i] = *(const bf16x8*)&As[(wm + i * 16 + ml) * 40 + qd * 8];
#pragma unroll
    for (int j = 0; j < 4; ++j)
      bfr[j] = *(const bf16x8*)&Bs[(wn + j * 16 + ml) * 40 + qd * 8];
#pragma unroll
    for (int i = 0; i < 4; ++i)
#pragma unroll
      for (int j = 0; j < 4; ++j)
        acc[i][j] = __builtin_amdgcn_mfma_f32_16x16x32_bf16(af[i], bfr[j], acc[i][j], 0, 0, 0);
  }
#pragma unroll
  for (int i = 0; i < 4; ++i) {
    const int rr = m0 + wm + i * 16 + qd * 4;
#pragma unroll
    for (int j = 0; j < 4; ++j) {
      const int cc = n0 + wn + j * 16 + ml;
      const float bb = bias[cc];
#pragma unroll
      for (int p = 0; p < 4; ++p) {
        float v = acc[i][j][p] + bb;
        if (EPI == 1) v = gelu_f(v);
        C[(size_t)(rr + p) * N + cc] = f2bf(v);
      }
    }
  }
}

// ---------------- gather expert outputs back + final residual add ----------
__global__ __launch_bounds__(256) void moe_gather(
    const u16* __restrict__ outm, const int* __restrict__ topi,
    const int* __restrict__ pos, const float* __restrict__ tw,
    float* __restrict__ y) {
  const int t = blockIdx.x;
  const int d = threadIdx.x * 4;
  float a0 = 0.f, a1 = 0.f, a2 = 0.f, a3 = 0.f;
#pragma unroll
  for (int k = 0; k < 2; ++k) {
    const int i = k * T_TOKENS + t;
    const int p = pos[i];
    if (p < CAPACITY) {
      const int e = topi[i];
      const float wg = tw[i];
      const ushort4 r = *(const ushort4*)(outm + ((size_t)e * CAPACITY + p) * 1024 + d);
      a0 = fmaf(wg, bf2f(r.x), a0);
      a1 = fmaf(wg, bf2f(r.y), a1);
      a2 = fmaf(wg, bf2f(r.z), a2);
      a3 = fmaf(wg, bf2f(r.w), a3);
    }
  }
  float4* op = (float4*)(y + (size_t)t * 1024 + d);
  float4 cur = *op;
  cur.x += a0; cur.y += a1; cur.z += a2; cur.w += a3;
  *op = cur;
}

// ---------------- workspace layout ----------------------------------------
static const size_t OFF_STATS = 0;                       // me_acc 32B
static const size_t OFF_TOPI = 0x100;                    // 8192 i32
static const size_t OFF_TW = 0x8100;                     // 8192 f32
static const size_t OFF_POS = 0x10100;                   // 8192 i32
static const size_t OFF_H = 0x20000;                     // 16MB f32 (h, then attn o)
static const size_t OFF_QKV = OFF_H + 0x1000000;         // 48MB f32 (qkv; later outm+h2f)
static const size_t OFF_H2F = OFF_QKV + 0x1400000;       // 16MB f32 (inside qkv region)
static const size_t OFF_H2B = OFF_QKV + 0x3000000;       // 8MB bf16
static const size_t OFF_BUF = OFF_H2B + 0x800000;        // 20MB bf16
static const size_t OFF_WT = OFF_BUF + 0x1400000;        // 64MB (wqkvT/woT f16, then w1t/w2t bf16)
static const size_t OFF_HH = OFF_WT + 0x4000000;         // 80MB bf16
static const size_t WS_NEED = OFF_HH + 0x5000000;        // ~236 MB

extern "C" void kernel_launch(void* const* d_in, const int* in_sizes, int n_in,
                              void* d_out, int out_size, void* d_ws, size_t ws_size,
                              hipStream_t stream) {
  (void)in_sizes; (void)n_in; (void)out_size;
  if (ws_size < WS_NEED) return;  // fail visibly rather than corrupt

  const float* x = (const float*)d_in[0];
  const float* cosb = (const float*)d_in[1];
  const float* sinb = (const float*)d_in[2];
  const float* ln1g = (const float*)d_in[3];
  const float* ln1b = (const float*)d_in[4];
  const float* ln2g = (const float*)d_in[5];
  const float* ln2b = (const float*)d_in[6];
  const float* wqkv = (const float*)d_in[7];
  const float* bqkv = (const float*)d_in[8];
  const float* wo = (const float*)d_in[9];
  const float* bo = (const float*)d_in[10];
  const float* gatew = (const float*)d_in[11];
  const float* w1 = (const float*)d_in[12];
  const float* b1 = (const float*)d_in[13];
  const float* w2 = (const float*)d_in[14];
  const float* b2 = (const float*)d_in[15];
  float* out = (float*)d_out;

  char* ws = (char*)d_ws;
  float* me_acc = (float*)(ws + OFF_STATS);
  int* topi = (int*)(ws + OFF_TOPI);
  float* tw = (float*)(ws + OFF_TW);
  int* pos = (int*)(ws + OFF_POS);
  float* h = (float*)(ws + OFF_H);
  float* o = (float*)(ws + OFF_H);      // reuse (h dead after QKV GEMM)
  float* qkv = (float*)(ws + OFF_QKV);
  u16* outm = (u16*)(ws + OFF_QKV);     // reuse (qkv dead after attention)
  float* h2f = (float*)(ws + OFF_H2F);
  u16* h2b = (u16*)(ws + OFF_H2B);
  u16* buf = (u16*)(ws + OFF_BUF);
  u16* wt = (u16*)(ws + OFF_WT);
  f16* wqkvTh = (f16*)(ws + OFF_WT);                 // 6 MB
  f16* wqkvTl = (f16*)(ws + OFF_WT + 0x600000);      // 6 MB
  f16* woTh = (f16*)(ws + OFF_WT + 0xC00000);        // 2 MB
  f16* woTl = (f16*)(ws + OFF_WT + 0xE00000);        // 2 MB (dead before w1t)
  u16* hh = (u16*)(ws + OFF_HH);

  hipMemsetAsync(me_acc, 0, 64, stream);
  hipMemsetAsync(buf, 0, (size_t)8 * CAPACITY * 1024 * 2, stream);

  // pre-gate path: split-fp16 3-pass MFMA (rel err ~2e-7 -> routing exact)
  ln_kernel<<<4096, 256, 0, stream>>>(x, ln1g, ln1b, h, (u16*)nullptr);
  transpose_f32_f16hl<<<dim3(96, 32), 256, 0, stream>>>(wqkv, wqkvTh, wqkvTl, 1024, 3072);
  gemm_f16x3_bt<0><<<dim3(24, 32), 256, 0, stream>>>(h, wqkvTh, wqkvTl, bqkv, nullptr,
                                                     qkv, 4096, 3072, 1024);
  rope_kernel<<<4096, 256, 0, stream>>>(qkv, cosb, sinb);
  transpose_f32_f16hl<<<dim3(32, 32), 256, 0, stream>>>(wo, woTh, woTl, 1024, 1024);
  attn_mfma<<<dim3(32, 32), 256, 0, stream>>>(qkv, o);
  gemm_f16x3_bt<1><<<dim3(8, 32), 256, 0, stream>>>(o, woTh, woTl, bo, x,
                                                    out, 4096, 1024, 1024);
  ln_kernel<<<4096, 256, 0, stream>>>(out, ln2g, ln2b, h2f, h2b);
  gate_kernel<<<1024, 256, 0, stream>>>(h2f, gatew, topi, tw, me_acc);
  route_kernel<<<1, 256, 0, stream>>>(topi, pos, me_acc, out + 4194304);

  // MoE experts: bf16 MFMA (smooth path)
  moe_scatter<<<8192, 128, 0, stream>>>(h2b, topi, pos, buf);
  transpose_f32_bf16<<<dim3(128, 32, 8), 256, 0, stream>>>(w1, wt, 1024, 4096, 1024L * 4096);
  bgemm_bt<1><<<dim3(32, 10, 8), 256, 0, stream>>>(buf, wt, b1, hh, 1280, 4096, 1024,
                                                   1280L * 1024, 4096L * 1024, 4096, 1280L * 4096);
  transpose_f32_bf16<<<dim3(32, 128, 8), 256, 0, stream>>>(w2, wt, 4096, 1024, 4096L * 1024);
  bgemm_bt<0><<<dim3(8, 10, 8), 256, 0, stream>>>(hh, wt, b2, outm, 1280, 1024, 4096,
                                                  1280L * 4096, 1024L * 4096, 1024, 1280L * 1024);
  moe_gather<<<4096, 256, 0, stream>>>(outm, topi, pos, tw, out);
}

// Round 3
// 1067.769 us; speedup vs baseline: 2.0271x; 1.3943x over previous
//
#include <hip/hip_runtime.h>

// Round 3: kill the gate_kernel atomic storm (32768 same-address global
// atomicAdds -> 423 us at 0.6% VALUBusy). Gate now writes per-token prob
// vectors to workspace; route_kernel (already a single-block full scan)
// reduces them deterministically.

typedef unsigned short u16;
typedef short bf16x8 __attribute__((ext_vector_type(8)));
typedef float f32x4 __attribute__((ext_vector_type(4)));
typedef _Float16 f16;
typedef f16 f16x8 __attribute__((ext_vector_type(8)));
typedef f16 f16x4 __attribute__((ext_vector_type(4)));

#define T_TOKENS 4096
#define SEQ      2048
#define CAPACITY 1280

__device__ __forceinline__ u16 f2bf(float f) {
  unsigned int u = __float_as_uint(f);
  return (u16)((u + 0x7FFFu + ((u >> 16) & 1u)) >> 16);
}
__device__ __forceinline__ float bf2f(u16 h) {
  return __uint_as_float(((unsigned int)h) << 16);
}
__device__ __forceinline__ float gelu_f(float x) {
  float x3 = x * x * x;
  float t = tanhf(0.7978845608028654f * (x + 0.044715f * x3));
  return 0.5f * x * (1.0f + t);
}

// ---------------- LayerNorm (fp32 in, fp32 and/or bf16 out) ----------------
__global__ __launch_bounds__(256) void ln_kernel(
    const float* __restrict__ x, const float* __restrict__ g,
    const float* __restrict__ bt, float* __restrict__ of32,
    u16* __restrict__ obf) {
  const int t = blockIdx.x, tid = threadIdx.x;
  float4 v = ((const float4*)(x + (size_t)t * 1024))[tid];
  float s = v.x + v.y + v.z + v.w;
  float sq = v.x * v.x + v.y * v.y + v.z * v.z + v.w * v.w;
#pragma unroll
  for (int d = 1; d < 64; d <<= 1) {
    s += __shfl_xor(s, d);
    sq += __shfl_xor(sq, d);
  }
  __shared__ float red[8];
  if ((tid & 63) == 0) { red[tid >> 6] = s; red[4 + (tid >> 6)] = sq; }
  __syncthreads();
  s = red[0] + red[1] + red[2] + red[3];
  sq = red[4] + red[5] + red[6] + red[7];
  const float mu = s * (1.0f / 1024.0f);
  const float var = sq * (1.0f / 1024.0f) - mu * mu;
  const float rs = rsqrtf(var + 1e-6f);
  float4 gv = ((const float4*)g)[tid];
  float4 bv = ((const float4*)bt)[tid];
  float4 o;
  o.x = (v.x - mu) * rs * gv.x + bv.x;
  o.y = (v.y - mu) * rs * gv.y + bv.y;
  o.z = (v.z - mu) * rs * gv.z + bv.z;
  o.w = (v.w - mu) * rs * gv.w + bv.w;
  if (of32) ((float4*)(of32 + (size_t)t * 1024))[tid] = o;
  if (obf) {
    ushort4 ob;
    ob.x = f2bf(o.x); ob.y = f2bf(o.y); ob.z = f2bf(o.z); ob.w = f2bf(o.w);
    ((ushort4*)(obf + (size_t)t * 1024))[tid] = ob;
  }
}

// ------- transpose fp32 [R][C] -> f16 hi/lo [C][R] (weight prep) ----------
__global__ __launch_bounds__(256) void transpose_f32_f16hl(
    const float* __restrict__ in, f16* __restrict__ outh, f16* __restrict__ outl,
    int R, int C) {
  __shared__ float tile[32][33];
  const int c0 = blockIdx.x * 32, r0 = blockIdx.y * 32;
  const int tx = threadIdx.x & 31, ty = threadIdx.x >> 5;
#pragma unroll
  for (int i = 0; i < 32; i += 8)
    tile[ty + i][tx] = in[(size_t)(r0 + ty + i) * C + c0 + tx];
  __syncthreads();
#pragma unroll
  for (int i = 0; i < 32; i += 8) {
    const float v = tile[tx][ty + i];
    const f16 hi = (f16)v;
    const size_t idx = (size_t)(c0 + ty + i) * R + r0 + tx;
    outh[idx] = hi;
    outl[idx] = (f16)(v - (float)hi);
  }
}

// ------- split-fp16 3-pass MFMA GEMM: C = A[M,K]@BT[N,K]^T + bias (+res) ---
template <int EPI>
__global__ __launch_bounds__(256, 2) void gemm_f16x3_bt(
    const float* __restrict__ A, const f16* __restrict__ Bth,
    const f16* __restrict__ Btl, const float* __restrict__ bias,
    const float* __restrict__ res, float* __restrict__ C, int M, int N, int K) {
  __shared__ f16 Ah[128 * 40], Al[128 * 40], Bh[128 * 40], Bl[128 * 40];
  const int tid = threadIdx.x, lane = tid & 63, w = tid >> 6;
  const int qd = lane >> 4, ml = lane & 15;
  const int m0 = blockIdx.y * 128, n0 = blockIdx.x * 128;
  const int wm = (w & 1) * 64, wn = (w >> 1) * 64;
  f32x4 acc[4][4] = {};

  const int sr = tid >> 1, sc = (tid & 1) * 16;
  const float* gA = A + (size_t)(m0 + sr) * K + sc;
  const f16* gBh = Bth + (size_t)(n0 + sr) * K + sc;
  const f16* gBl = Btl + (size_t)(n0 + sr) * K + sc;
  f16* lAh = &Ah[sr * 40 + sc];
  f16* lAl = &Al[sr * 40 + sc];
  f16* lBh = &Bh[sr * 40 + sc];
  f16* lBl = &Bl[sr * 40 + sc];

  for (int k0 = 0; k0 < K; k0 += 32) {
    const float4 a0 = *(const float4*)(gA + k0);
    const float4 a1 = *(const float4*)(gA + k0 + 4);
    const float4 a2 = *(const float4*)(gA + k0 + 8);
    const float4 a3 = *(const float4*)(gA + k0 + 12);
    const uint4 bh0 = *(const uint4*)(gBh + k0);
    const uint4 bh1 = *(const uint4*)(gBh + k0 + 8);
    const uint4 bl0 = *(const uint4*)(gBl + k0);
    const uint4 bl1 = *(const uint4*)(gBl + k0 + 8);
    const float af[16] = {a0.x, a0.y, a0.z, a0.w, a1.x, a1.y, a1.z, a1.w,
                          a2.x, a2.y, a2.z, a2.w, a3.x, a3.y, a3.z, a3.w};
    f16x8 h0, h1, l0, l1;
#pragma unroll
    for (int ii = 0; ii < 8; ++ii) {
      f16 hi = (f16)af[ii];
      h0[ii] = hi;
      l0[ii] = (f16)(af[ii] - (float)hi);
      f16 hi2 = (f16)af[8 + ii];
      h1[ii] = hi2;
      l1[ii] = (f16)(af[8 + ii] - (float)hi2);
    }
    __syncthreads();
    *(f16x8*)lAh = h0; *(f16x8*)(lAh + 8) = h1;
    *(f16x8*)lAl = l0; *(f16x8*)(lAl + 8) = l1;
    *(uint4*)lBh = bh0; *(uint4*)(lBh + 8) = bh1;
    *(uint4*)lBl = bl0; *(uint4*)(lBl + 8) = bl1;
    __syncthreads();
    f16x8 fah[4], fal[4], fbh[4], fbl[4];
#pragma unroll
    for (int i = 0; i < 4; ++i) {
      fah[i] = *(const f16x8*)&Ah[(wm + i * 16 + ml) * 40 + qd * 8];
      fal[i] = *(const f16x8*)&Al[(wm + i * 16 + ml) * 40 + qd * 8];
    }
#pragma unroll
    for (int j = 0; j < 4; ++j) {
      fbh[j] = *(const f16x8*)&Bh[(wn + j * 16 + ml) * 40 + qd * 8];
      fbl[j] = *(const f16x8*)&Bl[(wn + j * 16 + ml) * 40 + qd * 8];
    }
#pragma unroll
    for (int i = 0; i < 4; ++i)
#pragma unroll
      for (int j = 0; j < 4; ++j) {
        acc[i][j] = __builtin_amdgcn_mfma_f32_16x16x32_f16(fah[i], fbh[j], acc[i][j], 0, 0, 0);
        acc[i][j] = __builtin_amdgcn_mfma_f32_16x16x32_f16(fah[i], fbl[j], acc[i][j], 0, 0, 0);
        acc[i][j] = __builtin_amdgcn_mfma_f32_16x16x32_f16(fal[i], fbh[j], acc[i][j], 0, 0, 0);
      }
  }
#pragma unroll
  for (int i = 0; i < 4; ++i) {
    const int rr = m0 + wm + i * 16 + qd * 4;
#pragma unroll
    for (int j = 0; j < 4; ++j) {
      const int cc = n0 + wn + j * 16 + ml;
      const float bb = bias[cc];
#pragma unroll
      for (int p = 0; p < 4; ++p) {
        float v = acc[i][j][p] + bb;
        if (EPI == 1) v += res[(size_t)(rr + p) * N + cc];
        C[(size_t)(rr + p) * N + cc] = v;
      }
    }
  }
}

// ---------------- RoPE (in-place on fp32 qkv, q pre-scaled by 1/8) ---------
__global__ __launch_bounds__(256) void rope_kernel(
    float* __restrict__ qkv, const float* __restrict__ cosb,
    const float* __restrict__ sinb) {
  const int t = blockIdx.x;
  const int s = t & (SEQ - 1);
  float* row = qkv + (size_t)t * 3072;
  const int tid = threadIdx.x;
#pragma unroll
  for (int it = 0; it < 4; ++it) {
    const int p = tid + it * 256;           // 1024 pairs
    const int sec = p >> 9;                 // 0=q, 1=k
    const int rem = p & 511;
    const int h = rem >> 5, d = rem & 31;
    const int col = sec * 1024 + h * 64 + d;
    const float c1 = cosb[s * 64 + d], s1 = sinb[s * 64 + d];
    const float c2 = cosb[s * 64 + d + 32], s2 = sinb[s * 64 + d + 32];
    const float a = row[col], b = row[col + 32];
    float na = a * c1 - b * s1;
    float nb = b * c2 + a * s2;
    if (sec == 0) { na *= 0.125f; nb *= 0.125f; }
    row[col] = na;
    row[col + 32] = nb;
  }
}

// ---------------- split-fp16 MFMA flash attention --------------------------
__global__ __launch_bounds__(256) void attn_mfma(
    const float* __restrict__ qkv, float* __restrict__ o) {
  const int bh = blockIdx.y, b = bh >> 4, h = bh & 15;
  const int tid = threadIdx.x, w = tid >> 6, lane = tid & 63;
  const int quad = lane >> 4, ml = lane & 15;
  const int q0 = blockIdx.x * 64;
  const float* base = qkv + (size_t)b * SEQ * 3072 + h * 64;

  __shared__ f16 Kh[64 * 72], Kl[64 * 72];  // [key][d]   (B-frag for QK)
  __shared__ f16 Vh[64 * 72], Vl[64 * 72];  // [d][key]   (B-frag for PV)
  __shared__ f16 Ph[64 * 72], Pl[64 * 72];  // [q][key]   (A-frag for PV)

  f16x8 qh[2], ql[2];
  {
    const float* qrow = base + (size_t)(q0 + w * 16 + ml) * 3072;
#pragma unroll
    for (int ks = 0; ks < 2; ++ks) {
      const float4 a = *(const float4*)(qrow + ks * 32 + quad * 8);
      const float4 c = *(const float4*)(qrow + ks * 32 + quad * 8 + 4);
      const float f[8] = {a.x, a.y, a.z, a.w, c.x, c.y, c.z, c.w};
#pragma unroll
      for (int ii = 0; ii < 8; ++ii) {
        f16 hi = (f16)f[ii];
        qh[ks][ii] = hi;
        ql[ks][ii] = (f16)(f[ii] - (float)hi);
      }
    }
  }

  float m_i[4] = {-1e30f, -1e30f, -1e30f, -1e30f};
  float l_i[4] = {0.f, 0.f, 0.f, 0.f};
  f32x4 accO[4] = {};

  const int skey = tid >> 2, scg = (tid & 3) * 16;
  const int sd0 = (tid & 15) * 4, sk0 = (tid >> 4) * 4;

  for (int c0 = 0; c0 < SEQ; c0 += 64) {
    __syncthreads();
    {
      const float* kr = base + 1024 + (size_t)(c0 + skey) * 3072 + scg;
      const float4 r0 = ((const float4*)kr)[0];
      const float4 r1 = ((const float4*)kr)[1];
      const float4 r2 = ((const float4*)kr)[2];
      const float4 r3 = ((const float4*)kr)[3];
      const float kf[16] = {r0.x, r0.y, r0.z, r0.w, r1.x, r1.y, r1.z, r1.w,
                            r2.x, r2.y, r2.z, r2.w, r3.x, r3.y, r3.z, r3.w};
      f16x8 h0, h1, l0, l1;
#pragma unroll
      for (int ii = 0; ii < 8; ++ii) {
        f16 hi = (f16)kf[ii];
        h0[ii] = hi;
        l0[ii] = (f16)(kf[ii] - (float)hi);
        f16 hi2 = (f16)kf[8 + ii];
        h1[ii] = hi2;
        l1[ii] = (f16)(kf[8 + ii] - (float)hi2);
      }
      *(f16x8*)&Kh[skey * 72 + scg] = h0;
      *(f16x8*)&Kh[skey * 72 + scg + 8] = h1;
      *(f16x8*)&Kl[skey * 72 + scg] = l0;
      *(f16x8*)&Kl[skey * 72 + scg + 8] = l1;

      float4 rv[4];
#pragma unroll
      for (int i = 0; i < 4; ++i)
        rv[i] = *(const float4*)(base + 2048 + (size_t)(c0 + sk0 + i) * 3072 + sd0);
#pragma unroll
      for (int dd = 0; dd < 4; ++dd) {
        f16x4 vh4, vl4;
#pragma unroll
        for (int i = 0; i < 4; ++i) {
          const float fv = ((const float*)&rv[i])[dd];
          f16 hi = (f16)fv;
          vh4[i] = hi;
          vl4[i] = (f16)(fv - (float)hi);
        }
        *(f16x4*)&Vh[(sd0 + dd) * 72 + sk0] = vh4;
        *(f16x4*)&Vl[(sd0 + dd) * 72 + sk0] = vl4;
      }
    }
    __syncthreads();

    f32x4 s[4] = {};
#pragma unroll
    for (int ks = 0; ks < 2; ++ks)
#pragma unroll
      for (int j = 0; j < 4; ++j) {
        const f16x8 kh = *(const f16x8*)&Kh[(j * 16 + ml) * 72 + ks * 32 + quad * 8];
        const f16x8 kl = *(const f16x8*)&Kl[(j * 16 + ml) * 72 + ks * 32 + quad * 8];
        s[j] = __builtin_amdgcn_mfma_f32_16x16x32_f16(qh[ks], kh, s[j], 0, 0, 0);
        s[j] = __builtin_amdgcn_mfma_f32_16x16x32_f16(qh[ks], kl, s[j], 0, 0, 0);
        s[j] = __builtin_amdgcn_mfma_f32_16x16x32_f16(ql[ks], kh, s[j], 0, 0, 0);
      }

    float alpha[4];
#pragma unroll
    for (int p = 0; p < 4; ++p) {
      float mx = fmaxf(fmaxf(s[0][p], s[1][p]), fmaxf(s[2][p], s[3][p]));
      mx = fmaxf(mx, __shfl_xor(mx, 1));
      mx = fmaxf(mx, __shfl_xor(mx, 2));
      mx = fmaxf(mx, __shfl_xor(mx, 4));
      mx = fmaxf(mx, __shfl_xor(mx, 8));
      const float mn = fmaxf(m_i[p], mx);
      const float al = __expf(m_i[p] - mn);
      float rs = 0.f;
#pragma unroll
      for (int j = 0; j < 4; ++j) {
        const float e = __expf(s[j][p] - mn);
        s[j][p] = e;
        rs += e;
      }
      rs += __shfl_xor(rs, 1);
      rs += __shfl_xor(rs, 2);
      rs += __shfl_xor(rs, 4);
      rs += __shfl_xor(rs, 8);
      m_i[p] = mn;
      l_i[p] = l_i[p] * al + rs;
      alpha[p] = al;
    }
#pragma unroll
    for (int j = 0; j < 4; ++j)
#pragma unroll
      for (int p = 0; p < 4; ++p) accO[j][p] *= alpha[p];

#pragma unroll
    for (int j = 0; j < 4; ++j)
#pragma unroll
      for (int p = 0; p < 4; ++p) {
        const float v = s[j][p];
        const f16 hi = (f16)v;
        const int row = w * 16 + quad * 4 + p, col = ml + 16 * j;
        Ph[row * 72 + col] = hi;
        Pl[row * 72 + col] = (f16)(v - (float)hi);
      }

#pragma unroll
    for (int ks = 0; ks < 2; ++ks) {
      const f16x8 pah = *(const f16x8*)&Ph[(w * 16 + ml) * 72 + ks * 32 + quad * 8];
      const f16x8 pal = *(const f16x8*)&Pl[(w * 16 + ml) * 72 + ks * 32 + quad * 8];
#pragma unroll
      for (int j = 0; j < 4; ++j) {
        const f16x8 vbh = *(const f16x8*)&Vh[(j * 16 + ml) * 72 + ks * 32 + quad * 8];
        const f16x8 vbl = *(const f16x8*)&Vl[(j * 16 + ml) * 72 + ks * 32 + quad * 8];
        accO[j] = __builtin_amdgcn_mfma_f32_16x16x32_f16(pah, vbh, accO[j], 0, 0, 0);
        accO[j] = __builtin_amdgcn_mfma_f32_16x16x32_f16(pah, vbl, accO[j], 0, 0, 0);
        accO[j] = __builtin_amdgcn_mfma_f32_16x16x32_f16(pal, vbh, accO[j], 0, 0, 0);
      }
    }
  }
  const int trow = q0 + w * 16 + quad * 4;
#pragma unroll
  for (int p = 0; p < 4; ++p) {
    const float inv = 1.0f / l_i[p];
    const size_t ob = (size_t)(b * SEQ + trow + p) * 1024 + h * 64 + ml;
#pragma unroll
    for (int j = 0; j < 4; ++j) o[ob + j * 16] = accO[j][p] * inv;
  }
}

// ---------------- gate: fp32 logits, softmax, top-2; probs -> workspace ----
__global__ __launch_bounds__(256) void gate_kernel(
    const float* __restrict__ h2, const float* __restrict__ gw,
    int* __restrict__ topi, float* __restrict__ tw, float* __restrict__ me_part) {
  const int tid = threadIdx.x, w = tid >> 6, lane = tid & 63;
  const int t = blockIdx.x * 4 + w;
  const float* xr = h2 + (size_t)t * 1024;
  float acc[8] = {0.f, 0.f, 0.f, 0.f, 0.f, 0.f, 0.f, 0.f};
#pragma unroll
  for (int i = 0; i < 16; ++i) {
    const int d = lane + i * 64;
    const float xv = xr[d];
    const float4 g0 = ((const float4*)(gw + (size_t)d * 8))[0];
    const float4 g1 = ((const float4*)(gw + (size_t)d * 8))[1];
    acc[0] = fmaf(xv, g0.x, acc[0]); acc[1] = fmaf(xv, g0.y, acc[1]);
    acc[2] = fmaf(xv, g0.z, acc[2]); acc[3] = fmaf(xv, g0.w, acc[3]);
    acc[4] = fmaf(xv, g1.x, acc[4]); acc[5] = fmaf(xv, g1.y, acc[5]);
    acc[6] = fmaf(xv, g1.z, acc[6]); acc[7] = fmaf(xv, g1.w, acc[7]);
  }
#pragma unroll
  for (int e = 0; e < 8; ++e) {
    float v = acc[e];
    v += __shfl_xor(v, 1); v += __shfl_xor(v, 2); v += __shfl_xor(v, 4);
    v += __shfl_xor(v, 8); v += __shfl_xor(v, 16); v += __shfl_xor(v, 32);
    acc[e] = v;
  }
  if (lane == 0) {
    float mx = acc[0];
#pragma unroll
    for (int e = 1; e < 8; ++e) mx = fmaxf(mx, acc[e]);
    float ex[8], ssum = 0.f;
#pragma unroll
    for (int e = 0; e < 8; ++e) { ex[e] = __expf(acc[e] - mx); ssum += ex[e]; }
    const float inv = 1.f / ssum;
    float p[8];
#pragma unroll
    for (int e = 0; e < 8; ++e) p[e] = ex[e] * inv;
    int i1 = 0; float v1 = p[0];
#pragma unroll
    for (int e = 1; e < 8; ++e) if (p[e] > v1) { v1 = p[e]; i1 = e; }
    int i2 = (i1 == 0) ? 1 : 0; float v2 = p[i2];
#pragma unroll
    for (int e = 0; e < 8; ++e) if (e != i1 && p[e] > v2) { v2 = p[e]; i2 = e; }
    const float wn = 1.f / (v1 + v2);
    topi[t] = i1; topi[T_TOKENS + t] = i2;
    tw[t] = v1 * wn; tw[T_TOKENS + t] = v2 * wn;
    float4* mp = (float4*)(me_part + (size_t)t * 8);
    mp[0] = make_float4(p[0], p[1], p[2], p[3]);
    mp[1] = make_float4(p[4], p[5], p[6], p[7]);
  }
}

// ---------------- routing: stable per-expert rank + me/aux reduction -------
__global__ __launch_bounds__(256) void route_kernel(
    const int* __restrict__ topi, const float* __restrict__ me_part,
    int* __restrict__ pos, float* __restrict__ aux_out) {
  __shared__ int cnt[256][8];
  __shared__ float fme[256][8];
  __shared__ int tot[8];
  __shared__ float sme[8];
  const int tid = threadIdx.x;
  int lc[8] = {0, 0, 0, 0, 0, 0, 0, 0};
  const int i0 = tid * 32;
  for (int j = 0; j < 32; ++j) lc[topi[i0 + j]]++;
  float fm[8] = {0.f, 0.f, 0.f, 0.f, 0.f, 0.f, 0.f, 0.f};
  for (int r = tid; r < T_TOKENS; r += 256) {
    const float4 p0 = ((const float4*)(me_part + (size_t)r * 8))[0];
    const float4 p1 = ((const float4*)(me_part + (size_t)r * 8))[1];
    fm[0] += p0.x; fm[1] += p0.y; fm[2] += p0.z; fm[3] += p0.w;
    fm[4] += p1.x; fm[5] += p1.y; fm[6] += p1.z; fm[7] += p1.w;
  }
#pragma unroll
  for (int e = 0; e < 8; ++e) { cnt[tid][e] = lc[e]; fme[tid][e] = fm[e]; }
  __syncthreads();
  if (tid < 8) {
    int run = 0;
    float s = 0.f;
    for (int j = 0; j < 256; ++j) {
      const int v = cnt[j][tid];
      cnt[j][tid] = run;
      run += v;
      s += fme[j][tid];
    }
    tot[tid] = run;
    sme[tid] = s;
  }
  __syncthreads();
  int base[8];
#pragma unroll
  for (int e = 0; e < 8; ++e) base[e] = cnt[tid][e];
  for (int j = 0; j < 32; ++j) {
    const int e = topi[i0 + j];
    pos[i0 + j] = base[e]++;
  }
  if (tid == 0) {
    float aux = 0.f;
    for (int e = 0; e < 8; ++e) {
      const float me = sme[e] / 4096.0f;
      const float ce = (float)tot[e] / (4096.0f * 2.0f);
      aux += me * ce;
    }
    aux_out[0] = 8.0f * aux;
  }
}

// ---------------- scatter tokens to expert buffers (bf16) ------------------
__global__ __launch_bounds__(128) void moe_scatter(
    const u16* __restrict__ h2b, const int* __restrict__ topi,
    const int* __restrict__ pos, u16* __restrict__ buf) {
  const int i = blockIdx.x;
  const int p = pos[i];
  if (p >= CAPACITY) return;
  const int e = topi[i];
  const int t = i & (T_TOKENS - 1);
  const uint4* src = (const uint4*)(h2b + (size_t)t * 1024);
  uint4* dst = (uint4*)(buf + ((size_t)e * CAPACITY + p) * 1024);
  dst[threadIdx.x] = src[threadIdx.x];
}

// ---------------- fp32 -> bf16 transposing converter (batched) -------------
__global__ __launch_bounds__(256) void transpose_f32_bf16(
    const float* __restrict__ in, u16* __restrict__ out, int R, int C, long sz) {
  const float* ip = in + (size_t)blockIdx.z * sz;
  u16* op = out + (size_t)blockIdx.z * sz;
  __shared__ float tile[32][33];
  const int c0 = blockIdx.x * 32, r0 = blockIdx.y * 32;
  const int tx = threadIdx.x & 31, ty = threadIdx.x >> 5;
#pragma unroll
  for (int i = 0; i < 32; i += 8)
    tile[ty + i][tx] = ip[(size_t)(r0 + ty + i) * C + c0 + tx];
  __syncthreads();
#pragma unroll
  for (int i = 0; i < 32; i += 8)
    op[(size_t)(c0 + ty + i) * R + r0 + tx] = f2bf(tile[tx][ty + i]);
}

// ---------------- bf16 MFMA GEMM: C = A[M,K] @ BT[N,K]^T + bias ------------
template <int EPI>
__global__ __launch_bounds__(256, 2) void bgemm_bt(
    const u16* __restrict__ Ab, const u16* __restrict__ BTb,
    const float* __restrict__ biasb, u16* __restrict__ Cb,
    int M, int N, int K, long sA, long sB, long sBias, long sC) {
  const int e = blockIdx.z;
  const u16* A = Ab + (size_t)e * sA;
  const u16* BT = BTb + (size_t)e * sB;
  const float* bias = biasb + (size_t)e * sBias;
  u16* C = Cb + (size_t)e * sC;

  __shared__ u16 As[128 * 40];
  __shared__ u16 Bs[128 * 40];
  const int tid = threadIdx.x, lane = tid & 63, w = tid >> 6;
  const int qd = lane >> 4, ml = lane & 15;
  const int m0 = blockIdx.y * 128, n0 = blockIdx.x * 128;
  const int wm = (w & 1) * 64, wn = (w >> 1) * 64;
  f32x4 acc[4][4] = {};

  const int sr = tid >> 1, sh = (tid & 1) * 16;
  const u16* gA = A + (size_t)(m0 + sr) * K + sh;
  const u16* gB = BT + (size_t)(n0 + sr) * K + sh;
  u16* lA = &As[sr * 40 + sh];
  u16* lB = &Bs[sr * 40 + sh];

  for (int k0 = 0; k0 < K; k0 += 32) {
    const uint4 av0 = *(const uint4*)(gA + k0);
    const uint4 av1 = *(const uint4*)(gA + k0 + 8);
    const uint4 bv0 = *(const uint4*)(gB + k0);
    const uint4 bv1 = *(const uint4*)(gB + k0 + 8);
    __syncthreads();
    *(uint4*)lA = av0; *(uint4*)(lA + 8) = av1;
    *(uint4*)lB = bv0; *(uint4*)(lB + 8) = bv1;
    __syncthreads();
    bf16x8 af[4], bfr[4];
#pragma unroll
    for (int i = 0; i < 4; ++i)
      af[i] = *(const bf16x8*)&As[(wm + i * 16 + ml) * 40 + qd * 8];
#pragma unroll
    for (int j = 0; j < 4; ++j)
      bfr[j] = *(const bf16x8*)&Bs[(wn + j * 16 + ml) * 40 + qd * 8];
#pragma unroll
    for (int i = 0; i < 4; ++i)
#pragma unroll
      for (int j = 0; j < 4; ++j)
        acc[i][j] = __builtin_amdgcn_mfma_f32_16x16x32_bf16(af[i], bfr[j], acc[i][j], 0, 0, 0);
  }
#pragma unroll
  for (int i = 0; i < 4; ++i) {
    const int rr = m0 + wm + i * 16 + qd * 4;
#pragma unroll
    for (int j = 0; j < 4; ++j) {
      const int cc = n0 + wn + j * 16 + ml;
      const float bb = bias[cc];
#pragma unroll
      for (int p = 0; p < 4; ++p) {
        float v = acc[i][j][p] + bb;
        if (EPI == 1) v = gelu_f(v);
        C[(size_t)(rr + p) * N + cc] = f2bf(v);
      }
    }
  }
}

// ---------------- gather expert outputs back + final residual add ----------
__global__ __launch_bounds__(256) void moe_gather(
    const u16* __restrict__ outm, const int* __restrict__ topi,
    const int* __restrict__ pos, const float* __restrict__ tw,
    float* __restrict__ y) {
  const int t = blockIdx.x;
  const int d = threadIdx.x * 4;
  float a0 = 0.f, a1 = 0.f, a2 = 0.f, a3 = 0.f;
#pragma unroll
  for (int k = 0; k < 2; ++k) {
    const int i = k * T_TOKENS + t;
    const int p = pos[i];
    if (p < CAPACITY) {
      const int e = topi[i];
      const float wg = tw[i];
      const ushort4 r = *(const ushort4*)(outm + ((size_t)e * CAPACITY + p) * 1024 + d);
      a0 = fmaf(wg, bf2f(r.x), a0);
      a1 = fmaf(wg, bf2f(r.y), a1);
      a2 = fmaf(wg, bf2f(r.z), a2);
      a3 = fmaf(wg, bf2f(r.w), a3);
    }
  }
  float4* op = (float4*)(y + (size_t)t * 1024 + d);
  float4 cur = *op;
  cur.x += a0; cur.y += a1; cur.z += a2; cur.w += a3;
  *op = cur;
}

// ---------------- workspace layout ----------------------------------------
static const size_t OFF_TOPI = 0x100;                    // 8192 i32
static const size_t OFF_TW = 0x8100;                     // 8192 f32
static const size_t OFF_POS = 0x10100;                   // 8192 i32
static const size_t OFF_H = 0x20000;                     // 16MB f32 (h, then attn o)
static const size_t OFF_QKV = OFF_H + 0x1000000;         // 48MB f32 (qkv; later outm+h2f)
static const size_t OFF_H2F = OFF_QKV + 0x1400000;       // 16MB f32 (inside qkv region)
static const size_t OFF_H2B = OFF_QKV + 0x3000000;       // 8MB bf16
static const size_t OFF_BUF = OFF_H2B + 0x800000;        // 20MB bf16
static const size_t OFF_WT = OFF_BUF + 0x1400000;        // 64MB (wT f16 / me_part / w1t,w2t)
static const size_t OFF_HH = OFF_WT + 0x4000000;         // 80MB bf16
static const size_t WS_NEED = OFF_HH + 0x5000000;        // ~236 MB

extern "C" void kernel_launch(void* const* d_in, const int* in_sizes, int n_in,
                              void* d_out, int out_size, void* d_ws, size_t ws_size,
                              hipStream_t stream) {
  (void)in_sizes; (void)n_in; (void)out_size;
  if (ws_size < WS_NEED) return;  // fail visibly rather than corrupt

  const float* x = (const float*)d_in[0];
  const float* cosb = (const float*)d_in[1];
  const float* sinb = (const float*)d_in[2];
  const float* ln1g = (const float*)d_in[3];
  const float* ln1b = (const float*)d_in[4];
  const float* ln2g = (const float*)d_in[5];
  const float* ln2b = (const float*)d_in[6];
  const float* wqkv = (const float*)d_in[7];
  const float* bqkv = (const float*)d_in[8];
  const float* wo = (const float*)d_in[9];
  const float* bo = (const float*)d_in[10];
  const float* gatew = (const float*)d_in[11];
  const float* w1 = (const float*)d_in[12];
  const float* b1 = (const float*)d_in[13];
  const float* w2 = (const float*)d_in[14];
  const float* b2 = (const float*)d_in[15];
  float* out = (float*)d_out;

  char* ws = (char*)d_ws;
  int* topi = (int*)(ws + OFF_TOPI);
  float* tw = (float*)(ws + OFF_TW);
  int* pos = (int*)(ws + OFF_POS);
  float* h = (float*)(ws + OFF_H);
  float* o = (float*)(ws + OFF_H);      // reuse (h dead after QKV GEMM)
  float* qkv = (float*)(ws + OFF_QKV);
  u16* outm = (u16*)(ws + OFF_QKV);     // reuse (qkv dead after attention)
  float* h2f = (float*)(ws + OFF_H2F);
  u16* h2b = (u16*)(ws + OFF_H2B);
  u16* buf = (u16*)(ws + OFF_BUF);
  u16* wt = (u16*)(ws + OFF_WT);
  f16* wqkvTh = (f16*)(ws + OFF_WT);                 // 6 MB
  f16* wqkvTl = (f16*)(ws + OFF_WT + 0x600000);      // 6 MB
  f16* woTh = (f16*)(ws + OFF_WT + 0xC00000);        // 2 MB
  f16* woTl = (f16*)(ws + OFF_WT + 0xE00000);        // 2 MB
  // me_part: 4096x8 f32 = 128 KB. Lives in the WT region, which is dead
  // between the WO GEMM (last user of woT*) and the w1 transpose (first
  // writer of wt). gate/route run exactly in that window.
  float* me_part = (float*)(ws + OFF_WT + 0x1000000);
  u16* hh = (u16*)(ws + OFF_HH);

  hipMemsetAsync(buf, 0, (size_t)8 * CAPACITY * 1024 * 2, stream);

  // pre-gate path: split-fp16 3-pass MFMA (rel err ~2e-7 -> routing exact)
  ln_kernel<<<4096, 256, 0, stream>>>(x, ln1g, ln1b, h, (u16*)nullptr);
  transpose_f32_f16hl<<<dim3(96, 32), 256, 0, stream>>>(wqkv, wqkvTh, wqkvTl, 1024, 3072);
  gemm_f16x3_bt<0><<<dim3(24, 32), 256, 0, stream>>>(h, wqkvTh, wqkvTl, bqkv, nullptr,
                                                     qkv, 4096, 3072, 1024);
  rope_kernel<<<4096, 256, 0, stream>>>(qkv, cosb, sinb);
  transpose_f32_f16hl<<<dim3(32, 32), 256, 0, stream>>>(wo, woTh, woTl, 1024, 1024);
  attn_mfma<<<dim3(32, 32), 256, 0, stream>>>(qkv, o);
  gemm_f16x3_bt<1><<<dim3(8, 32), 256, 0, stream>>>(o, woTh, woTl, bo, x,
                                                    out, 4096, 1024, 1024);
  ln_kernel<<<4096, 256, 0, stream>>>(out, ln2g, ln2b, h2f, h2b);
  gate_kernel<<<1024, 256, 0, stream>>>(h2f, gatew, topi, tw, me_part);
  route_kernel<<<1, 256, 0, stream>>>(topi, me_part, pos, out + 4194304);

  // MoE experts: bf16 MFMA (smooth path)
  moe_scatter<<<8192, 128, 0, stream>>>(h2b, topi, pos, buf);
  transpose_f32_bf16<<<dim3(128, 32, 8), 256, 0, stream>>>(w1, wt, 1024, 4096, 1024L * 4096);
  bgemm_bt<1><<<dim3(32, 10, 8), 256, 0, stream>>>(buf, wt, b1, hh, 1280, 4096, 1024,
                                                   1280L * 1024, 4096L * 1024, 4096, 1280L * 4096);
  transpose_f32_bf16<<<dim3(32, 128, 8), 256, 0, stream>>>(w2, wt, 4096, 1024, 4096L * 1024);
  bgemm_bt<0><<<dim3(8, 10, 8), 256, 0, stream>>>(hh, wt, b2, outm, 1280, 1024, 4096,
                                                  1280L * 4096, 1024L * 4096, 1024, 1280L * 1024);
  moe_gather<<<4096, 256, 0, stream>>>(outm, topi, pos, tw, out);
}